// Round 1
// baseline (7224.598 us; speedup 1.0000x reference)
//
#include <hip/hip_runtime.h>
#include <math.h>

#define NN 32768
#define NE 524288

// ---------------------------------------------------------------------------
// helpers
// ---------------------------------------------------------------------------
__device__ __forceinline__ float siluf(float x){
  return x * __builtin_amdgcn_rcpf(1.0f + __expf(-x));
}

__device__ const int d_PL1[11] = {0,1,2,0,1,1,2,0,1,2,2};
__device__ const int d_PL2[11] = {0,1,2,1,0,2,1,2,1,0,2};
__device__ const int d_PL3[11] = {0,0,0,1,1,1,1,2,2,2,2};

// ---------------------------------------------------------------------------
// CG init kernel (exact port of _cg_su2 / _c2r / _cg_real, f64, one-time)
// Output: cgout[p*125 + (a*5+b)*5 + c], zero-padded to 5x5x5 per path.
// ---------------------------------------------------------------------------
__device__ double factd(int n){ double r=1.0; for(int i=2;i<=n;++i) r*=(double)i; return r; }

__device__ void c2r_build(int l, double* Qr, double* Qi){
  int n=2*l+1;
  for (int i=0;i<25;++i){ Qr[i]=0.0; Qi[i]=0.0; }
  Qr[l*n+l]=1.0;
  const double is2 = 0.7071067811865476;
  for (int m=1;m<=l;++m){
    double sgn = (m&1)? -1.0 : 1.0;
    Qr[(l+m)*n+(l+m)] = sgn*is2;
    Qr[(l+m)*n+(l-m)] = is2;
    Qi[(l-m)*n+(l-m)] = is2;
    Qi[(l-m)*n+(l+m)] = -sgn*is2;
  }
}

__global__ void cg_kernel(float* __restrict__ cgout){
  int tid = threadIdx.x;
  for (int i=tid; i<11*125; i+=blockDim.x) cgout[i]=0.0f;
  __syncthreads();
  if (tid >= 11) return;
  const int p = tid;
  const int l1=d_PL1[p], l2=d_PL2[p], l3=d_PL3[p];
  const int n1=2*l1+1, n2=2*l2+1, n3=2*l3+1;

  double C[125];
  for (int i=0;i<125;++i) C[i]=0.0;
  for (int m1=-l1;m1<=l1;++m1)
    for (int m2=-l2;m2<=l2;++m2){
      int m3=m1+m2;
      if (m3 < -l3 || m3 > l3) continue;
      double pref = sqrt((double)(2*l3+1)*factd(l3+l1-l2)*factd(l3-l1+l2)*factd(l1+l2-l3)/factd(l1+l2+l3+1));
      pref *= sqrt(factd(l3+m3)*factd(l3-m3)*factd(l1-m1)*factd(l1+m1)*factd(l2-m2)*factd(l2+m2));
      double s=0.0;
      for (int k=0;k<=l1+l2-l3;++k){
        int t1=l1+l2-l3-k, t2=l1-m1-k, t3=l2+m2-k, t4=l3-l2+m1+k, t5=l3-l1-m2+k;
        if (t1<0||t2<0||t3<0||t4<0||t5<0) continue;
        double d = factd(k)*factd(t1)*factd(t2)*factd(t3)*factd(t4)*factd(t5);
        s += ((k&1)? -1.0:1.0)/d;
      }
      C[((m1+l1)*n2 + (m2+l2))*n3 + (m3+l3)] = pref*s;
    }

  double Q1r[25],Q1i[25],Q2r[25],Q2i[25],Q3r[25],Q3i[25];
  c2r_build(l1,Q1r,Q1i);
  c2r_build(l2,Q2r,Q2i);
  c2r_build(l3,Q3r,Q3i);

  double Rre[125], Rim[125];
  double maxim = 0.0;
  for (int a=0;a<n1;++a)
    for (int b=0;b<n2;++b)
      for (int c=0;c<n3;++c){
        double re=0.0, im=0.0;
        for (int i=0;i<n1;++i)
          for (int j=0;j<n2;++j)
            for (int k=0;k<n3;++k){
              double cv = C[(i*n2+j)*n3+k];
              if (cv==0.0) continue;
              double q1r=Q1r[a*n1+i], q1i=-Q1i[a*n1+i];   // conj
              double q2r=Q2r[b*n2+j], q2i=-Q2i[b*n2+j];   // conj
              double q3r=Q3r[c*n3+k], q3i=Q3i[c*n3+k];
              double X = q1r*q2r - q1i*q2i;
              double Y = q1r*q2i + q1i*q2r;
              re += cv*(X*q3r - Y*q3i);
              im += cv*(X*q3i + Y*q3r);
            }
        int idx = (a*n2+b)*n3+c;
        Rre[idx]=re; Rim[idx]=im;
        maxim = fmax(maxim, fabs(im));
      }
  bool useim = (maxim >= 1e-10);
  for (int a=0;a<n1;++a)
    for (int b=0;b<n2;++b)
      for (int c=0;c<n3;++c){
        int idx=(a*n2+b)*n3+c;
        cgout[p*125 + (a*5+b)*5 + c] = (float)(useim? Rim[idx] : Rre[idx]);
      }
}

// ---------------------------------------------------------------------------
// Node up-projection: mtab[n][0:16]=f0@Wup0, [16:64]=m1 (c*3+i), [64:144]=m2,
// all * 1/sqrt(CH)=0.25
// ---------------------------------------------------------------------------
__global__ __launch_bounds__(256) void node_up_kernel(
    const float* __restrict__ nf,
    const float* __restrict__ W0,
    const float* __restrict__ W1,
    const float* __restrict__ W2,
    float* __restrict__ mtab)
{
  int gidx = blockIdx.x*256 + threadIdx.x;
  if (gidx >= NN*144) return;
  int n = gidx/144;
  int col = gidx - n*144;
  const float* f = nf + (size_t)n*144;
  float acc = 0.f;
  if (col < 16){
    int o = col;
    #pragma unroll
    for (int c=0;c<16;++c) acc += f[c]*W0[c*16+o];
  } else if (col < 64){
    int idx = col-16;
    int o = idx/3, i = idx - o*3;
    #pragma unroll
    for (int c=0;c<16;++c) acc += f[16+c*3+i]*W1[c*16+o];
  } else {
    int idx = col-64;
    int o = idx/5, i = idx - o*5;
    #pragma unroll
    for (int c=0;c<16;++c) acc += f[64+c*5+i]*W2[c*16+o];
  }
  mtab[gidx] = 0.25f*acc;
}

// ---------------------------------------------------------------------------
// Fused edge kernel: radial basis + MLP (all weights via uniform s_load) +
// spherical harmonics + CG tensor product, atomicAdd into agg[receiver].
// Thread per edge. Channel halves (8 at a time) to cap VGPRs.
// ---------------------------------------------------------------------------
__global__ __launch_bounds__(256, 2) void edge_kernel(
    const float* __restrict__ vectors,
    const int* __restrict__ senders,
    const int* __restrict__ receivers,
    const float* __restrict__ Wm0,
    const float* __restrict__ Wm1,
    const float* __restrict__ Wm2,
    const float* __restrict__ mtab,
    const float* __restrict__ cgtab,
    float* __restrict__ agg)
{
  int e = blockIdx.x*256 + threadIdx.x;
  if (e >= NE) return;

  float vx = vectors[(size_t)e*3+0];
  float vy = vectors[(size_t)e*3+1];
  float vz = vectors[(size_t)e*3+2];
  float r2 = vx*vx + vy*vy + vz*vz;
  float r = sqrtf(r2);
  float safe = (r > 1e-9f) ? r : 1.0f;
  float inv_safe = 1.0f/safe;
  float ux=vx*inv_safe, uy=vy*inv_safe, uz=vz*inv_safe;

  // radial basis: rb[k-1] = sqrt(0.5)*sin(pi*x*k)/safe * env, env=0.5(cos(pi x)+1)
  const float PIf = 3.14159265358979f;
  float xc = fminf(r*0.25f, 1.0f);
  float s1 = __sinf(PIf*xc);
  float c1 = __cosf(PIf*xc);
  float env = 0.5f*(c1 + 1.0f);
  float pref = 0.70710678118f * env * inv_safe;
  float rb[8];
  {
    float sk=s1, ck=c1;
    rb[0]=pref*sk;
    #pragma unroll
    for (int k=1;k<8;++k){
      float sn = sk*c1 + ck*s1;
      float cn = ck*c1 - sk*s1;
      sk=sn; ck=cn;
      rb[k]=pref*sk;
    }
  }

  // layer 1: h = silu(rb @ Wm0 / sqrt(8))
  float h[64];
  #pragma unroll
  for (int o=0;o<64;++o) h[o]=0.f;
  #pragma unroll
  for (int i=0;i<8;++i){
    float ri = rb[i];
    #pragma unroll
    for (int o=0;o<64;++o) h[o] += ri*Wm0[i*64+o];
  }
  #pragma unroll
  for (int o=0;o<64;++o) h[o] = siluf(h[o]*0.3535533906f);

  // layer 2: h2 = silu(h @ Wm1 / 8)
  float h2[64];
  #pragma unroll
  for (int o=0;o<64;++o) h2[o]=0.f;
  #pragma unroll
  for (int i=0;i<64;++i){
    float hi = h[i];
    #pragma unroll
    for (int o=0;o<64;++o) h2[o] += hi*Wm1[i*64+o];
  }
  #pragma unroll
  for (int o=0;o<64;++o) h2[o] = siluf(h2[o]*0.125f);

  // spherical harmonics of u  (y1 = sqrt3*[y,z,x])
  const float SQ3  = 1.73205080757f;
  const float SQ15 = 3.87298334621f;
  float y1a = SQ3*uy, y1b = SQ3*uz, y1c = SQ3*ux;
  float y2a = SQ15*ux*uy;
  float y2b = SQ15*uy*uz;
  float y2c = 1.11803398875f*(3.f*uz*uz - 1.f);
  float y2d = SQ15*ux*uz;
  float y2e = 1.93649167310f*(ux*ux - uy*uy);
  float lenmask = (r == 0.0f) ? 0.0f : 1.0f;

  const size_t srow = (size_t)senders[e]*144;
  const size_t rrow = (size_t)receivers[e]*144;

  // groups by l3: paths [0,3), [3,7), [7,11)
  #pragma unroll 1
  for (int g=0; g<3; ++g){
    const int pstart = (g==0)?0:((g==1)?3:7);
    const int pend   = (g==0)?3:((g==1)?7:11);
    const int d3 = 2*g+1;
    const int b3 = (g==0)?0:((g==1)?16:64);
    const float invn = (g==0)?0.57735026919f:0.5f;
    const float msc = 0.125f * invn * lenmask;   // mix/8 * 1/PATH_NORM * mask

    #pragma unroll 1
    for (int half=0; half<2; ++half){
      float msg[8][5];
      #pragma unroll
      for (int c=0;c<8;++c){
        #pragma unroll
        for (int k=0;k<5;++k) msg[c][k]=0.f;
      }

      #pragma unroll 1
      for (int p=pstart; p<pend; ++p){
        const int l1=d_PL1[p], l2=d_PL2[p];
        const int d1=2*l1+1;
        const int xb=(l1==0)?0:((l1==1)?16:64);

        float yj0,yj1,yj2,yj3,yj4;
        if (l2==0){ yj0=1.f; yj1=0.f; yj2=0.f; yj3=0.f; yj4=0.f; }
        else if (l2==1){ yj0=y1a; yj1=y1b; yj2=y1c; yj3=0.f; yj4=0.f; }
        else { yj0=y2a; yj1=y2b; yj2=y2c; yj3=y2d; yj4=y2e; }

        // M[i][k] = sum_j y[j]*CG[i][j][k]  (padded 5x5, CG zero-padded)
        const float* cgp = cgtab + p*125;
        float M[5][5];
        #pragma unroll
        for (int iu=0;iu<5;++iu){
          #pragma unroll
          for (int k=0;k<5;++k){
            M[iu][k] = yj0*cgp[(iu*5+0)*5+k] + yj1*cgp[(iu*5+1)*5+k]
                     + yj2*cgp[(iu*5+2)*5+k] + yj3*cgp[(iu*5+3)*5+k]
                     + yj4*cgp[(iu*5+4)*5+k];
          }
        }

        // mix chunk for this path/half: mx[c] = sum_i h2[i]*Wm2[i][p*16+half*8+c]
        float mx[8];
        #pragma unroll
        for (int c=0;c<8;++c) mx[c]=0.f;
        const float* w2c = Wm2 + p*16 + half*8;
        #pragma unroll
        for (int i=0;i<64;++i){
          const float hi = h2[i];
          #pragma unroll
          for (int c=0;c<8;++c) mx[c] += hi * w2c[i*176+c];
        }

        // x gather + tensor product
        const float* xp = mtab + srow + xb + (size_t)(half*8)*d1;
        #pragma unroll
        for (int c=0;c<8;++c){
          float xv[5];
          #pragma unroll
          for (int iu=0;iu<5;++iu) xv[iu] = (iu<d1)? xp[c*d1+iu] : 0.f;
          const float wmx = mx[c]*msc;
          #pragma unroll
          for (int k=0;k<5;++k){
            float t = xv[0]*M[0][k]+xv[1]*M[1][k]+xv[2]*M[2][k]
                    + xv[3]*M[3][k]+xv[4]*M[4][k];
            msg[c][k] += wmx*t;
          }
        }
      } // paths

      // flush: atomicAdd into agg[receiver]
      const size_t rbase = rrow + b3 + (size_t)(half*8)*d3;
      #pragma unroll
      for (int c=0;c<8;++c){
        #pragma unroll
        for (int k=0;k<5;++k){
          if (k<d3) unsafeAtomicAdd(&agg[rbase + c*d3 + k], msg[c][k]);
        }
      }
    } // half
  } // group
}

// ---------------------------------------------------------------------------
// Final node update. agg may alias out (in-place): all loads precede all
// stores per lane; rows are wave-exclusive; no __restrict__ on agg/out.
// ---------------------------------------------------------------------------
__global__ __launch_bounds__(256) void node_out_kernel(
    const float* __restrict__ nf,
    const int* __restrict__ species,
    const float* __restrict__ Wd0,
    const float* __restrict__ Wd1,
    const float* __restrict__ Wd2,
    const float* __restrict__ Wsk0,
    const float* __restrict__ Wsk1,
    const float* __restrict__ Wsk2,
    const float* agg,
    float* out)
{
  int t = blockIdx.x*256 + threadIdx.x;
  int n = t >> 4;
  int o = t & 15;
  if (n >= NN) return;
  const float* an = agg + (size_t)n*144;
  const float* f  = nf  + (size_t)n*144;
  int sp = species[n];
  const float* wk0 = Wsk0 + sp*768;
  const float* wk1 = Wsk1 + sp*256;
  const float* wk2 = Wsk2 + sp*256;

  // s = 0.25*(a0@Wd0) + 0.25*(f0@Wsk0), a0 = agg*0.25
  float sa0=0,sa1=0,sa2=0, sf0=0,sf1=0,sf2=0;
  #pragma unroll
  for (int c=0;c<16;++c){
    float a = an[c], ff = f[c];
    sa0 += a*Wd0[c*48+o];
    sa1 += a*Wd0[c*48+16+o];
    sa2 += a*Wd0[c*48+32+o];
    sf0 += ff*wk0[c*48+o];
    sf1 += ff*wk0[c*48+16+o];
    sf2 += ff*wk0[c*48+32+o];
  }
  float s0 = 0.0625f*sa0 + 0.25f*sf0;
  float s1 = 0.0625f*sa1 + 0.25f*sf1;
  float s2 = 0.0625f*sa2 + 0.25f*sf2;
  float scv = siluf(s0);
  float g1  = siluf(s1);
  float g2  = siluf(s2);

  float v[3];
  #pragma unroll
  for (int i=0;i<3;++i){
    float av=0, fv=0;
    #pragma unroll
    for (int c=0;c<16;++c){
      av += an[16+c*3+i]*Wd1[c*16+o];
      fv += f[16+c*3+i]*wk1[c*16+o];
    }
    v[i] = (0.0625f*av + 0.25f*fv)*g1;
  }
  float q[5];
  #pragma unroll
  for (int i=0;i<5;++i){
    float av=0, fv=0;
    #pragma unroll
    for (int c=0;c<16;++c){
      av += an[64+c*5+i]*Wd2[c*16+o];
      fv += f[64+c*5+i]*wk2[c*16+o];
    }
    q[i] = (0.0625f*av + 0.25f*fv)*g2;
  }

  // all stores after all reads (in-place safe)
  float* on = out + (size_t)n*144;
  on[o] = scv;
  #pragma unroll
  for (int i=0;i<3;++i) on[16+o*3+i] = v[i];
  #pragma unroll
  for (int i=0;i<5;++i) on[64+o*5+i] = q[i];
}

// ---------------------------------------------------------------------------
extern "C" void kernel_launch(void* const* d_in, const int* in_sizes, int n_in,
                              void* d_out, int out_size, void* d_ws, size_t ws_size,
                              hipStream_t stream)
{
  const float* vectors    = (const float*)d_in[0];
  const float* node_feats = (const float*)d_in[1];
  const int*   species    = (const int*)d_in[2];
  const int*   senders    = (const int*)d_in[3];
  const int*   receivers  = (const int*)d_in[4];
  const float* W_up0 = (const float*)d_in[5];
  const float* W_up1 = (const float*)d_in[6];
  const float* W_up2 = (const float*)d_in[7];
  const float* Wm0   = (const float*)d_in[8];
  const float* Wm1   = (const float*)d_in[9];
  const float* Wm2   = (const float*)d_in[10];
  const float* Wd0   = (const float*)d_in[11];
  const float* Wd1   = (const float*)d_in[12];
  const float* Wd2   = (const float*)d_in[13];
  const float* Wsk0  = (const float*)d_in[14];
  const float* Wsk1  = (const float*)d_in[15];
  const float* Wsk2  = (const float*)d_in[16];
  float* out = (float*)d_out;
  float* ws  = (float*)d_ws;

  float* cgbuf = ws;             // 11*125 floats in first 2048 slots
  float* mtab  = ws + 2048;      // NN*144 floats
  size_t base  = 2048 + (size_t)NN*144;
  size_t need_sep_agg = (base + (size_t)NN*144)*sizeof(float);
  float* agg = (ws_size >= need_sep_agg) ? (ws + base) : out;

  hipMemsetAsync(agg, 0, (size_t)NN*144*sizeof(float), stream);
  cg_kernel<<<1, 128, 0, stream>>>(cgbuf);
  node_up_kernel<<<(NN*144)/256, 256, 0, stream>>>(node_feats, W_up0, W_up1, W_up2, mtab);
  edge_kernel<<<NE/256, 256, 0, stream>>>(vectors, senders, receivers,
                                          Wm0, Wm1, Wm2, mtab, cgbuf, agg);
  node_out_kernel<<<NN/16, 256, 0, stream>>>(node_feats, species,
                                             Wd0, Wd1, Wd2, Wsk0, Wsk1, Wsk2,
                                             agg, out);
}

// Round 2
// 4147.742 us; speedup vs baseline: 1.7418x; 1.7418x over previous
//
#include <hip/hip_runtime.h>
#include <math.h>

#define NN 32768
#define NE 524288

__device__ __forceinline__ float siluf(float x){
  return x * __builtin_amdgcn_rcpf(1.0f + __expf(-x));
}

// path tables (host-side mirror used for templates; device copy for cg kernel)
__device__ const int d_PL1[11] = {0,1,2,0,1,1,2,0,1,2,2};
__device__ const int d_PL2[11] = {0,1,2,1,0,2,1,2,1,0,2};
__device__ const int d_PL3[11] = {0,0,0,1,1,1,1,2,2,2,2};

// ---------------------------------------------------------------------------
// CG init: one thread per (path, a,b,c) slot of the zero-padded 5x5x5 table.
// All 11 paths have even l1+l2+l3 -> real part of the complex transform.
// 1/PATH_NORM[l3] folded in.
// ---------------------------------------------------------------------------
__device__ double factd(int n){ double r=1.0; for(int i=2;i<=n;++i) r*=(double)i; return r; }

__device__ double su2_elem(int l1,int l2,int l3,int m1,int m2){
  int m3=m1+m2;
  if (m3 < -l3 || m3 > l3) return 0.0;
  double pref = sqrt((double)(2*l3+1)*factd(l3+l1-l2)*factd(l3-l1+l2)*factd(l1+l2-l3)/factd(l1+l2+l3+1));
  pref *= sqrt(factd(l3+m3)*factd(l3-m3)*factd(l1-m1)*factd(l1+m1)*factd(l2-m2)*factd(l2+m2));
  double s=0.0;
  for (int k=0;k<=l1+l2-l3;++k){
    int t1=l1+l2-l3-k, t2=l1-m1-k, t3=l2+m2-k, t4=l3-l2+m1+k, t5=l3-l1-m2+k;
    if (t1<0||t2<0||t3<0||t4<0||t5<0) continue;
    double d = factd(k)*factd(t1)*factd(t2)*factd(t3)*factd(t4)*factd(t5);
    s += ((k&1)? -1.0:1.0)/d;
  }
  return pref*s;
}

// Q[l](a,i) element of the complex->real transform
__device__ void q_elem(int l,int a,int i,double& re,double& im){
  re=0.0; im=0.0;
  const double is2 = 0.7071067811865476;
  int m = a - l;
  if (m==0){ if (i==l) re=1.0; return; }
  if (m>0){
    if (i==l+m)      re = (m&1)? -is2: is2;
    else if (i==l-m) re = is2;
  } else {
    int mm=-m;
    if (i==l-mm)      im = is2;
    else if (i==l+mm) im = (mm&1)? is2 : -is2;  // -1j*(-1)^m/sqrt2
  }
}

__global__ void cg_kernel(float* __restrict__ cgout){
  int p = blockIdx.x;            // 11 blocks
  int t = threadIdx.x;           // 128 threads
  if (t >= 125) return;
  int a = t/25, b = (t/5)%5, c = t%5;
  int l1=d_PL1[p], l2=d_PL2[p], l3=d_PL3[p];
  int n1=2*l1+1, n2=2*l2+1, n3=2*l3+1;
  float outv = 0.0f;
  if (a<n1 && b<n2 && c<n3){
    double acc = 0.0;
    for (int i=0;i<n1;++i)
      for (int j=0;j<n2;++j){
        int m1=i-l1, m2=j-l2;
        int m3=m1+m2;
        if (m3 < -l3 || m3 > l3) continue;
        double cv = su2_elem(l1,l2,l3,m1,m2);
        if (cv==0.0) continue;
        int k = m3 + l3;
        double a1r,a1i,a2r,a2i,a3r,a3i;
        q_elem(l1,a,i,a1r,a1i);
        q_elem(l2,b,j,a2r,a2i);
        q_elem(l3,c,k,a3r,a3i);
        // Re[ conj(q1)*conj(q2)*q3 ]
        double re = (a1r*a2r - a1i*a2i)*a3r + (a1r*a2i + a1i*a2r)*a3i;
        acc += cv*re;
      }
    double invn = (l3==0)? 0.5773502691896258 : 0.5;
    outv = (float)(acc*invn);
  }
  cgout[p*125 + (a*5+b)*5 + c] = outv;
}

// ---------------------------------------------------------------------------
// Node up-projection: mtab[n][0:16]=f0@Wup0, [16:64]=m1 (c*3+i), [64:144]=m2
// (c*5+i), all * 0.25
// ---------------------------------------------------------------------------
__global__ __launch_bounds__(256) void node_up_kernel(
    const float* __restrict__ nf,
    const float* __restrict__ W0,
    const float* __restrict__ W1,
    const float* __restrict__ W2,
    float* __restrict__ mtab)
{
  int gidx = blockIdx.x*256 + threadIdx.x;
  if (gidx >= NN*144) return;
  int n = gidx/144;
  int col = gidx - n*144;
  const float* f = nf + (size_t)n*144;
  float acc = 0.f;
  if (col < 16){
    int o = col;
    #pragma unroll
    for (int c=0;c<16;++c) acc += f[c]*W0[c*16+o];
  } else if (col < 64){
    int idx = col-16;
    int o = idx/3, i = idx - o*3;
    #pragma unroll
    for (int c=0;c<16;++c) acc += f[16+c*3+i]*W1[c*16+o];
  } else {
    int idx = col-64;
    int o = idx/5, i = idx - o*5;
    #pragma unroll
    for (int c=0;c<16;++c) acc += f[64+c*5+i]*W2[c*16+o];
  }
  mtab[gidx] = 0.25f*acc;
}

// ---------------------------------------------------------------------------
// Stage 1: radial basis + layer1 + layer2 -> h2g[le][64]
// ---------------------------------------------------------------------------
__global__ __launch_bounds__(256) void mlp_h2_kernel(
    const float* __restrict__ vectors,
    const float* __restrict__ Wm0,
    const float* __restrict__ Wm1,
    int e0, int ecnt,
    float* __restrict__ h2g)
{
  int le = blockIdx.x*256 + threadIdx.x;
  if (le >= ecnt) return;
  int e = e0 + le;

  float vx = vectors[(size_t)e*3+0];
  float vy = vectors[(size_t)e*3+1];
  float vz = vectors[(size_t)e*3+2];
  float r = sqrtf(vx*vx + vy*vy + vz*vz);
  float safe = (r > 1e-9f) ? r : 1.0f;
  float inv_safe = 1.0f/safe;

  const float PIf = 3.14159265358979f;
  float xc = fminf(r*0.25f, 1.0f);
  float s1 = __sinf(PIf*xc);
  float c1 = __cosf(PIf*xc);
  float env = 0.5f*(c1 + 1.0f);
  float pref = 0.70710678118f * env * inv_safe;
  float rb[8];
  {
    float sk=s1, ck=c1;
    rb[0]=pref*sk;
    #pragma unroll
    for (int k=1;k<8;++k){
      float sn = sk*c1 + ck*s1;
      float cn = ck*c1 - sk*s1;
      sk=sn; ck=cn;
      rb[k]=pref*sk;
    }
  }

  float h[64];
  #pragma unroll
  for (int o=0;o<64;++o) h[o]=0.f;
  #pragma unroll
  for (int i=0;i<8;++i){
    float ri = rb[i];
    #pragma unroll
    for (int o=0;o<64;++o) h[o] += ri*Wm0[i*64+o];
  }
  #pragma unroll
  for (int o=0;o<64;++o) h[o] = siluf(h[o]*0.3535533906f);

  float* h2row = h2g + (size_t)le*64;
  #pragma unroll 1
  for (int oc=0;oc<4;++oc){
    float acc[16];
    #pragma unroll
    for (int c=0;c<16;++c) acc[c]=0.f;
    #pragma unroll
    for (int i=0;i<64;++i){
      float hi = h[i];
      #pragma unroll
      for (int c=0;c<16;++c) acc[c] += hi*Wm1[i*64+oc*16+c];
    }
    #pragma unroll
    for (int c=0;c<16;++c) h2row[oc*16+c] = siluf(acc[c]*0.125f);
  }
}

// ---------------------------------------------------------------------------
// Stage 2: mix[le][176] = (h2 @ Wm2) * 0.125 * (r!=0)
// ---------------------------------------------------------------------------
__global__ __launch_bounds__(256) void mix_kernel(
    const float* __restrict__ vectors,
    const float* __restrict__ Wm2,
    const float* __restrict__ h2g,
    int e0, int ecnt,
    float* __restrict__ mixb)
{
  int le = blockIdx.x*256 + threadIdx.x;
  if (le >= ecnt) return;
  int e = e0 + le;

  float h2[64];
  const float4* hp = (const float4*)(h2g + (size_t)le*64);
  #pragma unroll
  for (int w=0;w<16;++w){
    float4 v = hp[w];
    h2[4*w+0]=v.x; h2[4*w+1]=v.y; h2[4*w+2]=v.z; h2[4*w+3]=v.w;
  }

  float vx = vectors[(size_t)e*3+0];
  float vy = vectors[(size_t)e*3+1];
  float vz = vectors[(size_t)e*3+2];
  float r = sqrtf(vx*vx + vy*vy + vz*vz);
  float scale = (r == 0.0f) ? 0.0f : 0.125f;

  float* mrow = mixb + (size_t)le*176;
  #pragma unroll 1
  for (int oc=0;oc<11;++oc){
    float acc[16];
    #pragma unroll
    for (int c=0;c<16;++c) acc[c]=0.f;
    #pragma unroll
    for (int i=0;i<64;++i){
      float hi = h2[i];
      #pragma unroll
      for (int c=0;c<16;++c) acc[c] += hi*Wm2[i*176+oc*16+c];
    }
    #pragma unroll
    for (int c=0;c<16;++c) mrow[oc*16+c] = acc[c]*scale;
  }
}

// ---------------------------------------------------------------------------
// Stage 3: tensor product + scatter. Thread per (edge, channel-quarter).
// ---------------------------------------------------------------------------
template<int PIDX,int L1,int L2,int L3>
__device__ __forceinline__ void do_path(
    const float* __restrict__ cgtab,
    const float* __restrict__ mixrow,
    int c0,
    const float (&y1)[3], const float (&y2)[5],
    const float (&x0)[4], const float (&x1)[4][3], const float (&x2)[4][5],
    float (&msg0)[4], float (&msg1)[4][3], float (&msg2)[4][5])
{
  constexpr int d1=2*L1+1, d2=2*L2+1, d3=2*L3+1;
  const float* cgp = cgtab + PIDX*125;

  float yv[d2];
  if constexpr (L2==0){ yv[0]=1.0f; }
  else if constexpr (L2==1){ yv[0]=y1[0]; yv[1]=y1[1]; yv[2]=y1[2]; }
  else {
    #pragma unroll
    for (int j=0;j<5;++j) yv[j]=y2[j];
  }

  float M[d1][d3];
  #pragma unroll
  for (int iu=0;iu<d1;++iu){
    #pragma unroll
    for (int k=0;k<d3;++k){
      float acc = 0.f;
      #pragma unroll
      for (int j=0;j<d2;++j) acc += yv[j]*cgp[(iu*5+j)*5+k];
      M[iu][k]=acc;
    }
  }

  float mx[4];
  const float* mp = mixrow + PIDX*16 + c0;
  #pragma unroll
  for (int c=0;c<4;++c) mx[c]=mp[c];

  #pragma unroll
  for (int c=0;c<4;++c){
    #pragma unroll
    for (int k=0;k<d3;++k){
      float t = 0.f;
      #pragma unroll
      for (int iu=0;iu<d1;++iu){
        float xv = (L1==0)? x0[c] : (L1==1? x1[c][iu] : x2[c][iu]);
        t += xv*M[iu][k];
      }
      if constexpr (L3==0)      msg0[c]    += mx[c]*t;
      else if constexpr (L3==1) msg1[c][k] += mx[c]*t;
      else                      msg2[c][k] += mx[c]*t;
    }
  }
}

__global__ __launch_bounds__(256) void tp_kernel(
    const float* __restrict__ vectors,
    const int* __restrict__ senders,
    const int* __restrict__ receivers,
    const float* __restrict__ mtab,
    const float* __restrict__ cgtab,
    const float* __restrict__ mixb,
    int e0, int ecnt,
    float* __restrict__ agg)
{
  int t = blockIdx.x*256 + threadIdx.x;
  int le = t >> 2;
  if (le >= ecnt) return;
  int c0 = (t & 3)*4;
  int e = e0 + le;

  float vx = vectors[(size_t)e*3+0];
  float vy = vectors[(size_t)e*3+1];
  float vz = vectors[(size_t)e*3+2];
  float r = sqrtf(vx*vx + vy*vy + vz*vz);
  float safe = (r > 1e-9f) ? r : 1.0f;
  float inv_safe = 1.0f/safe;
  float ux=vx*inv_safe, uy=vy*inv_safe, uz=vz*inv_safe;

  const float SQ3  = 1.73205080757f;
  const float SQ15 = 3.87298334621f;
  float y1[3] = { SQ3*uy, SQ3*uz, SQ3*ux };
  float y2[5] = { SQ15*ux*uy, SQ15*uy*uz, 1.11803398875f*(3.f*uz*uz-1.f),
                  SQ15*ux*uz, 1.93649167310f*(ux*ux-uy*uy) };

  const float* xp = mtab + (size_t)senders[e]*144;
  float x0[4];
  float x1[4][3];
  float x2[4][5];
  #pragma unroll
  for (int c=0;c<4;++c) x0[c] = xp[c0+c];
  #pragma unroll
  for (int c=0;c<4;++c){
    #pragma unroll
    for (int i=0;i<3;++i) x1[c][i] = xp[16 + (c0+c)*3 + i];
  }
  #pragma unroll
  for (int c=0;c<4;++c){
    #pragma unroll
    for (int i=0;i<5;++i) x2[c][i] = xp[64 + (c0+c)*5 + i];
  }

  float msg0[4];
  float msg1[4][3];
  float msg2[4][5];
  #pragma unroll
  for (int c=0;c<4;++c){
    msg0[c]=0.f;
    #pragma unroll
    for (int i=0;i<3;++i) msg1[c][i]=0.f;
    #pragma unroll
    for (int i=0;i<5;++i) msg2[c][i]=0.f;
  }

  const float* mixrow = mixb + (size_t)le*176;

  do_path< 0,0,0,0>(cgtab,mixrow,c0,y1,y2,x0,x1,x2,msg0,msg1,msg2);
  do_path< 1,1,1,0>(cgtab,mixrow,c0,y1,y2,x0,x1,x2,msg0,msg1,msg2);
  do_path< 2,2,2,0>(cgtab,mixrow,c0,y1,y2,x0,x1,x2,msg0,msg1,msg2);
  do_path< 3,0,1,1>(cgtab,mixrow,c0,y1,y2,x0,x1,x2,msg0,msg1,msg2);
  do_path< 4,1,0,1>(cgtab,mixrow,c0,y1,y2,x0,x1,x2,msg0,msg1,msg2);
  do_path< 5,1,2,1>(cgtab,mixrow,c0,y1,y2,x0,x1,x2,msg0,msg1,msg2);
  do_path< 6,2,1,1>(cgtab,mixrow,c0,y1,y2,x0,x1,x2,msg0,msg1,msg2);
  do_path< 7,0,2,2>(cgtab,mixrow,c0,y1,y2,x0,x1,x2,msg0,msg1,msg2);
  do_path< 8,1,1,2>(cgtab,mixrow,c0,y1,y2,x0,x1,x2,msg0,msg1,msg2);
  do_path< 9,2,0,2>(cgtab,mixrow,c0,y1,y2,x0,x1,x2,msg0,msg1,msg2);
  do_path<10,2,2,2>(cgtab,mixrow,c0,y1,y2,x0,x1,x2,msg0,msg1,msg2);

  float* ag = agg + (size_t)receivers[e]*144;
  #pragma unroll
  for (int c=0;c<4;++c) unsafeAtomicAdd(&ag[c0+c], msg0[c]);
  #pragma unroll
  for (int c=0;c<4;++c){
    #pragma unroll
    for (int i=0;i<3;++i) unsafeAtomicAdd(&ag[16 + (c0+c)*3 + i], msg1[c][i]);
  }
  #pragma unroll
  for (int c=0;c<4;++c){
    #pragma unroll
    for (int i=0;i<5;++i) unsafeAtomicAdd(&ag[64 + (c0+c)*5 + i], msg2[c][i]);
  }
}

// ---------------------------------------------------------------------------
// Final node update. agg aliases out (in-place). All loads precede all stores
// per lane; 16-thread node-groups never span waves -> lockstep-safe.
// ---------------------------------------------------------------------------
__global__ __launch_bounds__(256) void node_out_kernel(
    const float* __restrict__ nf,
    const int* __restrict__ species,
    const float* __restrict__ Wd0,
    const float* __restrict__ Wd1,
    const float* __restrict__ Wd2,
    const float* __restrict__ Wsk0,
    const float* __restrict__ Wsk1,
    const float* __restrict__ Wsk2,
    const float* agg,
    float* out)
{
  int t = blockIdx.x*256 + threadIdx.x;
  int n = t >> 4;
  int o = t & 15;
  if (n >= NN) return;
  const float* an = agg + (size_t)n*144;
  const float* f  = nf  + (size_t)n*144;
  int sp = species[n];
  const float* wk0 = Wsk0 + sp*768;
  const float* wk1 = Wsk1 + sp*256;
  const float* wk2 = Wsk2 + sp*256;

  float sa0=0,sa1=0,sa2=0, sf0=0,sf1=0,sf2=0;
  #pragma unroll
  for (int c=0;c<16;++c){
    float a = an[c], ff = f[c];
    sa0 += a*Wd0[c*48+o];
    sa1 += a*Wd0[c*48+16+o];
    sa2 += a*Wd0[c*48+32+o];
    sf0 += ff*wk0[c*48+o];
    sf1 += ff*wk0[c*48+16+o];
    sf2 += ff*wk0[c*48+32+o];
  }
  float s0 = 0.0625f*sa0 + 0.25f*sf0;
  float s1 = 0.0625f*sa1 + 0.25f*sf1;
  float s2 = 0.0625f*sa2 + 0.25f*sf2;
  float scv = siluf(s0);
  float g1  = siluf(s1);
  float g2  = siluf(s2);

  float v[3];
  #pragma unroll
  for (int i=0;i<3;++i){
    float av=0, fv=0;
    #pragma unroll
    for (int c=0;c<16;++c){
      av += an[16+c*3+i]*Wd1[c*16+o];
      fv += f[16+c*3+i]*wk1[c*16+o];
    }
    v[i] = (0.0625f*av + 0.25f*fv)*g1;
  }
  float q[5];
  #pragma unroll
  for (int i=0;i<5;++i){
    float av=0, fv=0;
    #pragma unroll
    for (int c=0;c<16;++c){
      av += an[64+c*5+i]*Wd2[c*16+o];
      fv += f[64+c*5+i]*wk2[c*16+o];
    }
    q[i] = (0.0625f*av + 0.25f*fv)*g2;
  }

  float* on = out + (size_t)n*144;
  on[o] = scv;
  #pragma unroll
  for (int i=0;i<3;++i) on[16+o*3+i] = v[i];
  #pragma unroll
  for (int i=0;i<5;++i) on[64+o*5+i] = q[i];
}

// ---------------------------------------------------------------------------
extern "C" void kernel_launch(void* const* d_in, const int* in_sizes, int n_in,
                              void* d_out, int out_size, void* d_ws, size_t ws_size,
                              hipStream_t stream)
{
  const float* vectors    = (const float*)d_in[0];
  const float* node_feats = (const float*)d_in[1];
  const int*   species    = (const int*)d_in[2];
  const int*   senders    = (const int*)d_in[3];
  const int*   receivers  = (const int*)d_in[4];
  const float* W_up0 = (const float*)d_in[5];
  const float* W_up1 = (const float*)d_in[6];
  const float* W_up2 = (const float*)d_in[7];
  const float* Wm0   = (const float*)d_in[8];
  const float* Wm1   = (const float*)d_in[9];
  const float* Wm2   = (const float*)d_in[10];
  const float* Wd0   = (const float*)d_in[11];
  const float* Wd1   = (const float*)d_in[12];
  const float* Wd2   = (const float*)d_in[13];
  const float* Wsk0  = (const float*)d_in[14];
  const float* Wsk1  = (const float*)d_in[15];
  const float* Wsk2  = (const float*)d_in[16];
  float* out = (float*)d_out;
  float* ws  = (float*)d_ws;

  // ws layout: [cg 2048][mtab NN*144][h2g EC*64][mix EC*176]
  float* cgbuf = ws;
  float* mtab  = ws + 2048;
  size_t fixed = 2048 + (size_t)NN*144;
  size_t ws_f  = ws_size/4;
  size_t avail = (ws_f > fixed) ? (ws_f - fixed) : 0;
  long long EC = (long long)(avail/240);
  if (EC > NE) EC = NE;
  EC &= ~255LL;
  if (EC < 256) EC = 256;   // assumes ws >= ~19.2 MB (held in round 1)
  float* h2g  = ws + fixed;
  float* mixb = h2g + (size_t)EC*64;

  hipMemsetAsync(out, 0, (size_t)NN*144*sizeof(float), stream);
  cg_kernel<<<11, 128, 0, stream>>>(cgbuf);
  node_up_kernel<<<(NN*144)/256, 256, 0, stream>>>(node_feats, W_up0, W_up1, W_up2, mtab);

  for (long long e0 = 0; e0 < NE; e0 += EC){
    int ecnt = (int)(((NE - e0) < EC) ? (NE - e0) : EC);
    int gh = (ecnt + 255)/256;
    int gt = (ecnt*4 + 255)/256;
    mlp_h2_kernel<<<gh, 256, 0, stream>>>(vectors, Wm0, Wm1, (int)e0, ecnt, h2g);
    mix_kernel<<<gh, 256, 0, stream>>>(vectors, Wm2, h2g, (int)e0, ecnt, mixb);
    tp_kernel<<<gt, 256, 0, stream>>>(vectors, senders, receivers, mtab, cgbuf,
                                      mixb, (int)e0, ecnt, out);
  }

  node_out_kernel<<<NN/16, 256, 0, stream>>>(node_feats, species,
                                             Wd0, Wd1, Wd2, Wsk0, Wsk1, Wsk2,
                                             out, out);
}

// Round 3
// 988.184 us; speedup vs baseline: 7.3110x; 4.1973x over previous
//
#include <hip/hip_runtime.h>
#include <math.h>

#define NN 32768
#define NE 524288

__device__ __forceinline__ float siluf(float x){
  return x * __builtin_amdgcn_rcpf(1.0f + __expf(-x));
}

__device__ const int d_PL1[11] = {0,1,2,0,1,1,2,0,1,2,2};
__device__ const int d_PL2[11] = {0,1,2,1,0,2,1,2,1,0,2};
__device__ const int d_PL3[11] = {0,0,0,1,1,1,1,2,2,2,2};

// ---------------------------------------------------------------------------
// CG init (1/PATH_NORM folded in). All paths even l1+l2+l3 -> real part.
// ---------------------------------------------------------------------------
__device__ double factd(int n){ double r=1.0; for(int i=2;i<=n;++i) r*=(double)i; return r; }

__device__ double su2_elem(int l1,int l2,int l3,int m1,int m2){
  int m3=m1+m2;
  if (m3 < -l3 || m3 > l3) return 0.0;
  double pref = sqrt((double)(2*l3+1)*factd(l3+l1-l2)*factd(l3-l1+l2)*factd(l1+l2-l3)/factd(l1+l2+l3+1));
  pref *= sqrt(factd(l3+m3)*factd(l3-m3)*factd(l1-m1)*factd(l1+m1)*factd(l2-m2)*factd(l2+m2));
  double s=0.0;
  for (int k=0;k<=l1+l2-l3;++k){
    int t1=l1+l2-l3-k, t2=l1-m1-k, t3=l2+m2-k, t4=l3-l2+m1+k, t5=l3-l1-m2+k;
    if (t1<0||t2<0||t3<0||t4<0||t5<0) continue;
    double d = factd(k)*factd(t1)*factd(t2)*factd(t3)*factd(t4)*factd(t5);
    s += ((k&1)? -1.0:1.0)/d;
  }
  return pref*s;
}

__device__ void q_elem(int l,int a,int i,double& re,double& im){
  re=0.0; im=0.0;
  const double is2 = 0.7071067811865476;
  int m = a - l;
  if (m==0){ if (i==l) re=1.0; return; }
  if (m>0){
    if (i==l+m)      re = (m&1)? -is2: is2;
    else if (i==l-m) re = is2;
  } else {
    int mm=-m;
    if (i==l-mm)      im = is2;
    else if (i==l+mm) im = (mm&1)? is2 : -is2;
  }
}

__global__ void cg_kernel(float* __restrict__ cgout){
  int p = blockIdx.x;
  int t = threadIdx.x;
  if (t >= 125) return;
  int a = t/25, b = (t/5)%5, c = t%5;
  int l1=d_PL1[p], l2=d_PL2[p], l3=d_PL3[p];
  int n1=2*l1+1, n2=2*l2+1, n3=2*l3+1;
  float outv = 0.0f;
  if (a<n1 && b<n2 && c<n3){
    double acc = 0.0;
    for (int i=0;i<n1;++i)
      for (int j=0;j<n2;++j){
        int m1=i-l1, m2=j-l2;
        int m3=m1+m2;
        if (m3 < -l3 || m3 > l3) continue;
        double cv = su2_elem(l1,l2,l3,m1,m2);
        if (cv==0.0) continue;
        int k = m3 + l3;
        double a1r,a1i,a2r,a2i,a3r,a3i;
        q_elem(l1,a,i,a1r,a1i);
        q_elem(l2,b,j,a2r,a2i);
        q_elem(l3,c,k,a3r,a3i);
        double re = (a1r*a2r - a1i*a2i)*a3r + (a1r*a2i + a1i*a2r)*a3i;
        acc += cv*re;
      }
    double invn = (l3==0)? 0.5773502691896258 : 0.5;
    outv = (float)(acc*invn);
  }
  cgout[p*125 + (a*5+b)*5 + c] = outv;
}

// ---------------------------------------------------------------------------
// Node up-projection (mtab scaled by 0.25)
// ---------------------------------------------------------------------------
__global__ __launch_bounds__(256) void node_up_kernel(
    const float* __restrict__ nf,
    const float* __restrict__ W0,
    const float* __restrict__ W1,
    const float* __restrict__ W2,
    float* __restrict__ mtab)
{
  int gidx = blockIdx.x*256 + threadIdx.x;
  if (gidx >= NN*144) return;
  int n = gidx/144;
  int col = gidx - n*144;
  const float* f = nf + (size_t)n*144;
  float acc = 0.f;
  if (col < 16){
    int o = col;
    #pragma unroll
    for (int c=0;c<16;++c) acc += f[c]*W0[c*16+o];
  } else if (col < 64){
    int idx = col-16;
    int o = idx/3, i = idx - o*3;
    #pragma unroll
    for (int c=0;c<16;++c) acc += f[16+c*3+i]*W1[c*16+o];
  } else {
    int idx = col-64;
    int o = idx/5, i = idx - o*5;
    #pragma unroll
    for (int c=0;c<16;++c) acc += f[64+c*5+i]*W2[c*16+o];
  }
  mtab[gidx] = 0.25f*acc;
}

// ---------------------------------------------------------------------------
// CSR build: histogram, scan, scatter
// ---------------------------------------------------------------------------
__global__ __launch_bounds__(256) void hist_kernel(
    const int* __restrict__ recv, int* __restrict__ counts)
{
  int e = blockIdx.x*256 + threadIdx.x;
  if (e < NE) atomicAdd(&counts[recv[e]], 1);
}

__global__ __launch_bounds__(1024) void scan_kernel(
    const int* __restrict__ counts, int* __restrict__ offsets)
{
  __shared__ int part[1024];
  int t = threadIdx.x;
  int local[32];
  int s = 0;
  #pragma unroll
  for (int i=0;i<32;++i){ local[i]=counts[t*32+i]; s+=local[i]; }
  part[t]=s;
  __syncthreads();
  for (int off=1; off<1024; off<<=1){
    int v = (t>=off)? part[t-off] : 0;
    __syncthreads();
    part[t] += v;
    __syncthreads();
  }
  int run = part[t] - s;   // exclusive prefix of this thread's block of 32
  #pragma unroll
  for (int i=0;i<32;++i){ offsets[t*32+i]=run; run+=local[i]; }
  if (t==1023) offsets[NN]=run;
}

__global__ __launch_bounds__(256) void scatter_kernel(
    const int* __restrict__ recv, const int* __restrict__ offsets,
    int* __restrict__ cursor, int* __restrict__ edge_sorted)
{
  int e = blockIdx.x*256 + threadIdx.x;
  if (e < NE){
    int r = recv[e];
    int pos = atomicAdd(&cursor[r], 1);
    edge_sorted[offsets[r] + pos] = e;
  }
}

// ---------------------------------------------------------------------------
// Fused radial-basis + MLP + mix, over sorted edges of one node-chunk.
// Writes compacted mixb[slot][176], scaled by 0.125 * (r!=0).
// ---------------------------------------------------------------------------
__global__ __launch_bounds__(256) void edge_mix_kernel(
    const float* __restrict__ vectors,
    const int* __restrict__ edge_sorted,
    const int* __restrict__ offsets,
    const float* __restrict__ Wm0,
    const float* __restrict__ Wm1,
    const float* __restrict__ Wm2,
    int n0, int n1,
    float* __restrict__ mixb)
{
  int t = blockIdx.x*256 + threadIdx.x;
  int sbase = offsets[n0];
  int send  = offsets[n1];
  int s = sbase + t;
  if (s >= send) return;
  int e = edge_sorted[s];

  float vx = vectors[(size_t)e*3+0];
  float vy = vectors[(size_t)e*3+1];
  float vz = vectors[(size_t)e*3+2];
  float r = sqrtf(vx*vx + vy*vy + vz*vz);
  float safe = (r > 1e-9f) ? r : 1.0f;
  float inv_safe = 1.0f/safe;

  const float PIf = 3.14159265358979f;
  float xc = fminf(r*0.25f, 1.0f);
  float s1 = __sinf(PIf*xc);
  float c1 = __cosf(PIf*xc);
  float env = 0.5f*(c1 + 1.0f);
  float pref = 0.70710678118f * env * inv_safe;
  float rb[8];
  {
    float sk=s1, ck=c1;
    rb[0]=pref*sk;
    #pragma unroll
    for (int k=1;k<8;++k){
      float sn = sk*c1 + ck*s1;
      float cn = ck*c1 - sk*s1;
      sk=sn; ck=cn;
      rb[k]=pref*sk;
    }
  }

  float h[64];
  #pragma unroll
  for (int o=0;o<64;++o) h[o]=0.f;
  #pragma unroll
  for (int i=0;i<8;++i){
    float ri = rb[i];
    #pragma unroll
    for (int o=0;o<64;++o) h[o] += ri*Wm0[i*64+o];
  }
  #pragma unroll
  for (int o=0;o<64;++o) h[o] = siluf(h[o]*0.3535533906f);

  float h2[64];
  #pragma unroll 1
  for (int oc=0;oc<4;++oc){
    float acc[16];
    #pragma unroll
    for (int c=0;c<16;++c) acc[c]=0.f;
    #pragma unroll
    for (int i=0;i<64;++i){
      float hi = h[i];
      #pragma unroll
      for (int c=0;c<16;++c) acc[c] += hi*Wm1[i*64+oc*16+c];
    }
    #pragma unroll
    for (int c=0;c<16;++c) h2[oc*16+c] = siluf(acc[c]*0.125f);
  }

  float scale = (r == 0.0f) ? 0.0f : 0.125f;
  float* mrow = mixb + (size_t)t*176;
  #pragma unroll 1
  for (int oc=0;oc<11;++oc){
    float acc[16];
    #pragma unroll
    for (int c=0;c<16;++c) acc[c]=0.f;
    #pragma unroll
    for (int i=0;i<64;++i){
      float hi = h2[i];
      #pragma unroll
      for (int c=0;c<16;++c) acc[c] += hi*Wm2[i*176+oc*16+c];
    }
    #pragma unroll
    for (int w=0;w<4;++w){
      float4 v;
      v.x = acc[4*w+0]*scale; v.y = acc[4*w+1]*scale;
      v.z = acc[4*w+2]*scale; v.w = acc[4*w+3]*scale;
      *(float4*)(mrow + oc*16 + 4*w) = v;
    }
  }
}

// ---------------------------------------------------------------------------
// Tensor-product + gather per (node, channel-quarter). No atomics.
// ---------------------------------------------------------------------------
template<int PIDX,int L1,int L2,int L3>
__device__ __forceinline__ void do_path(
    const float* __restrict__ cgtab,
    const float* __restrict__ mixrow,
    int c0,
    const float (&y1)[3], const float (&y2)[5],
    const float (&x0)[4], const float (&x1)[4][3], const float (&x2)[4][5],
    float (&msg0)[4], float (&msg1)[4][3], float (&msg2)[4][5])
{
  constexpr int d1=2*L1+1, d2=2*L2+1, d3=2*L3+1;
  const float* cgp = cgtab + PIDX*125;

  float yv[d2];
  if constexpr (L2==0){ yv[0]=1.0f; }
  else if constexpr (L2==1){ yv[0]=y1[0]; yv[1]=y1[1]; yv[2]=y1[2]; }
  else {
    #pragma unroll
    for (int j=0;j<5;++j) yv[j]=y2[j];
  }

  float M[d1][d3];
  #pragma unroll
  for (int iu=0;iu<d1;++iu){
    #pragma unroll
    for (int k=0;k<d3;++k){
      float acc = 0.f;
      #pragma unroll
      for (int j=0;j<d2;++j) acc += yv[j]*cgp[(iu*5+j)*5+k];
      M[iu][k]=acc;
    }
  }

  float mx[4];
  const float* mp = mixrow + PIDX*16 + c0;
  #pragma unroll
  for (int c=0;c<4;++c) mx[c]=mp[c];

  #pragma unroll
  for (int c=0;c<4;++c){
    #pragma unroll
    for (int k=0;k<d3;++k){
      float t = 0.f;
      #pragma unroll
      for (int iu=0;iu<d1;++iu){
        float xv = (L1==0)? x0[c] : (L1==1? x1[c][iu] : x2[c][iu]);
        t += xv*M[iu][k];
      }
      if constexpr (L3==0)      msg0[c]    += mx[c]*t;
      else if constexpr (L3==1) msg1[c][k] += mx[c]*t;
      else                      msg2[c][k] += mx[c]*t;
    }
  }
}

__global__ __launch_bounds__(256) void gather_kernel(
    const float* __restrict__ vectors,
    const int* __restrict__ senders,
    const int* __restrict__ edge_sorted,
    const int* __restrict__ offsets,
    const float* __restrict__ mtab,
    const float* __restrict__ cgtab,
    const float* __restrict__ mixb,
    int n0, int n1,
    float* __restrict__ out)
{
  int t = blockIdx.x*256 + threadIdx.x;
  int n = n0 + (t >> 2);
  if (n >= n1) return;
  int c0 = (t & 3)*4;
  int cbase = offsets[n0];
  int j0 = offsets[n];
  int j1 = offsets[n+1];

  float msg0[4];
  float msg1[4][3];
  float msg2[4][5];
  #pragma unroll
  for (int c=0;c<4;++c){
    msg0[c]=0.f;
    #pragma unroll
    for (int i=0;i<3;++i) msg1[c][i]=0.f;
    #pragma unroll
    for (int i=0;i<5;++i) msg2[c][i]=0.f;
  }

  const float SQ3  = 1.73205080757f;
  const float SQ15 = 3.87298334621f;

  for (int j=j0; j<j1; ++j){
    int e = edge_sorted[j];
    float vx = vectors[(size_t)e*3+0];
    float vy = vectors[(size_t)e*3+1];
    float vz = vectors[(size_t)e*3+2];
    float r = sqrtf(vx*vx + vy*vy + vz*vz);
    float safe = (r > 1e-9f) ? r : 1.0f;
    float inv_safe = 1.0f/safe;
    float ux=vx*inv_safe, uy=vy*inv_safe, uz=vz*inv_safe;

    float y1[3] = { SQ3*uy, SQ3*uz, SQ3*ux };
    float y2[5] = { SQ15*ux*uy, SQ15*uy*uz, 1.11803398875f*(3.f*uz*uz-1.f),
                    SQ15*ux*uz, 1.93649167310f*(ux*ux-uy*uy) };

    const float* xp = mtab + (size_t)senders[e]*144;
    float x0[4];
    float x1[4][3];
    float x2[4][5];
    #pragma unroll
    for (int c=0;c<4;++c) x0[c] = xp[c0+c];
    #pragma unroll
    for (int c=0;c<4;++c){
      #pragma unroll
      for (int i=0;i<3;++i) x1[c][i] = xp[16 + (c0+c)*3 + i];
    }
    #pragma unroll
    for (int c=0;c<4;++c){
      #pragma unroll
      for (int i=0;i<5;++i) x2[c][i] = xp[64 + (c0+c)*5 + i];
    }

    const float* mixrow = mixb + (size_t)(j - cbase)*176;

    do_path< 0,0,0,0>(cgtab,mixrow,c0,y1,y2,x0,x1,x2,msg0,msg1,msg2);
    do_path< 1,1,1,0>(cgtab,mixrow,c0,y1,y2,x0,x1,x2,msg0,msg1,msg2);
    do_path< 2,2,2,0>(cgtab,mixrow,c0,y1,y2,x0,x1,x2,msg0,msg1,msg2);
    do_path< 3,0,1,1>(cgtab,mixrow,c0,y1,y2,x0,x1,x2,msg0,msg1,msg2);
    do_path< 4,1,0,1>(cgtab,mixrow,c0,y1,y2,x0,x1,x2,msg0,msg1,msg2);
    do_path< 5,1,2,1>(cgtab,mixrow,c0,y1,y2,x0,x1,x2,msg0,msg1,msg2);
    do_path< 6,2,1,1>(cgtab,mixrow,c0,y1,y2,x0,x1,x2,msg0,msg1,msg2);
    do_path< 7,0,2,2>(cgtab,mixrow,c0,y1,y2,x0,x1,x2,msg0,msg1,msg2);
    do_path< 8,1,1,2>(cgtab,mixrow,c0,y1,y2,x0,x1,x2,msg0,msg1,msg2);
    do_path< 9,2,0,2>(cgtab,mixrow,c0,y1,y2,x0,x1,x2,msg0,msg1,msg2);
    do_path<10,2,2,2>(cgtab,mixrow,c0,y1,y2,x0,x1,x2,msg0,msg1,msg2);
  }

  float* on = out + (size_t)n*144;
  #pragma unroll
  for (int c=0;c<4;++c) on[c0+c] = msg0[c];
  #pragma unroll
  for (int c=0;c<4;++c){
    #pragma unroll
    for (int i=0;i<3;++i) on[16 + (c0+c)*3 + i] = msg1[c][i];
  }
  #pragma unroll
  for (int c=0;c<4;++c){
    #pragma unroll
    for (int i=0;i<5;++i) on[64 + (c0+c)*5 + i] = msg2[c][i];
  }
}

// ---------------------------------------------------------------------------
// Final node update, in-place on out.
// ---------------------------------------------------------------------------
__global__ __launch_bounds__(256) void node_out_kernel(
    const float* __restrict__ nf,
    const int* __restrict__ species,
    const float* __restrict__ Wd0,
    const float* __restrict__ Wd1,
    const float* __restrict__ Wd2,
    const float* __restrict__ Wsk0,
    const float* __restrict__ Wsk1,
    const float* __restrict__ Wsk2,
    const float* agg,
    float* out)
{
  int t = blockIdx.x*256 + threadIdx.x;
  int n = t >> 4;
  int o = t & 15;
  if (n >= NN) return;
  const float* an = agg + (size_t)n*144;
  const float* f  = nf  + (size_t)n*144;
  int sp = species[n];
  const float* wk0 = Wsk0 + sp*768;
  const float* wk1 = Wsk1 + sp*256;
  const float* wk2 = Wsk2 + sp*256;

  float sa0=0,sa1=0,sa2=0, sf0=0,sf1=0,sf2=0;
  #pragma unroll
  for (int c=0;c<16;++c){
    float a = an[c], ff = f[c];
    sa0 += a*Wd0[c*48+o];
    sa1 += a*Wd0[c*48+16+o];
    sa2 += a*Wd0[c*48+32+o];
    sf0 += ff*wk0[c*48+o];
    sf1 += ff*wk0[c*48+16+o];
    sf2 += ff*wk0[c*48+32+o];
  }
  float s0 = 0.0625f*sa0 + 0.25f*sf0;
  float s1 = 0.0625f*sa1 + 0.25f*sf1;
  float s2 = 0.0625f*sa2 + 0.25f*sf2;
  float scv = siluf(s0);
  float g1  = siluf(s1);
  float g2  = siluf(s2);

  float v[3];
  #pragma unroll
  for (int i=0;i<3;++i){
    float av=0, fv=0;
    #pragma unroll
    for (int c=0;c<16;++c){
      av += an[16+c*3+i]*Wd1[c*16+o];
      fv += f[16+c*3+i]*wk1[c*16+o];
    }
    v[i] = (0.0625f*av + 0.25f*fv)*g1;
  }
  float q[5];
  #pragma unroll
  for (int i=0;i<5;++i){
    float av=0, fv=0;
    #pragma unroll
    for (int c=0;c<16;++c){
      av += an[64+c*5+i]*Wd2[c*16+o];
      fv += f[64+c*5+i]*wk2[c*16+o];
    }
    q[i] = (0.0625f*av + 0.25f*fv)*g2;
  }

  float* on = out + (size_t)n*144;
  on[o] = scv;
  #pragma unroll
  for (int i=0;i<3;++i) on[16+o*3+i] = v[i];
  #pragma unroll
  for (int i=0;i<5;++i) on[64+o*5+i] = q[i];
}

// ---------------------------------------------------------------------------
extern "C" void kernel_launch(void* const* d_in, const int* in_sizes, int n_in,
                              void* d_out, int out_size, void* d_ws, size_t ws_size,
                              hipStream_t stream)
{
  const float* vectors    = (const float*)d_in[0];
  const float* node_feats = (const float*)d_in[1];
  const int*   species    = (const int*)d_in[2];
  const int*   senders    = (const int*)d_in[3];
  const int*   receivers  = (const int*)d_in[4];
  const float* W_up0 = (const float*)d_in[5];
  const float* W_up1 = (const float*)d_in[6];
  const float* W_up2 = (const float*)d_in[7];
  const float* Wm0   = (const float*)d_in[8];
  const float* Wm1   = (const float*)d_in[9];
  const float* Wm2   = (const float*)d_in[10];
  const float* Wd0   = (const float*)d_in[11];
  const float* Wd1   = (const float*)d_in[12];
  const float* Wd2   = (const float*)d_in[13];
  const float* Wsk0  = (const float*)d_in[14];
  const float* Wsk1  = (const float*)d_in[15];
  const float* Wsk2  = (const float*)d_in[16];
  float* out = (float*)d_out;
  float* ws  = (float*)d_ws;

  // ws layout (floats/ints):
  // [cg 2048][mtab NN*144][counts NN][cursor NN][offsets NN+64][edge_sorted NE][mixb ...]
  float* cgbuf = ws;
  float* mtab  = ws + 2048;
  int* counts      = (int*)(ws + 2048 + (size_t)NN*144);
  int* cursor      = counts + NN;
  int* offsets     = cursor + NN;
  int* edge_sorted = offsets + NN + 64;
  float* mixb      = (float*)(edge_sorted + NE);

  size_t fixed_f = 2048 + (size_t)NN*144 + NN + NN + (NN+64) + NE;
  size_t ws_f = ws_size/4;
  long long cap = (ws_f > fixed_f) ? (long long)((ws_f - fixed_f)/176) : 0;
  if (cap > NE) cap = NE;
  // nodes per chunk: expected 16 edges/node; keep ~50% headroom in cap
  long long npc = cap/24;
  npc &= ~255LL;
  if (npc < 256) npc = 256;
  if (npc > NN) npc = NN;

  hipMemsetAsync(counts, 0, 2*(size_t)NN*sizeof(int), stream);
  cg_kernel<<<11, 128, 0, stream>>>(cgbuf);
  node_up_kernel<<<(NN*144)/256, 256, 0, stream>>>(node_feats, W_up0, W_up1, W_up2, mtab);
  hist_kernel<<<NE/256, 256, 0, stream>>>(receivers, counts);
  scan_kernel<<<1, 1024, 0, stream>>>(counts, offsets);
  scatter_kernel<<<NE/256, 256, 0, stream>>>(receivers, offsets, cursor, edge_sorted);

  int edge_grid = (int)((cap + 255)/256);
  for (long long n0 = 0; n0 < NN; n0 += npc){
    long long n1 = (n0 + npc < NN) ? (n0 + npc) : NN;
    int gather_grid = (int)(((n1 - n0)*4 + 255)/256);
    edge_mix_kernel<<<edge_grid, 256, 0, stream>>>(vectors, edge_sorted, offsets,
                                                   Wm0, Wm1, Wm2,
                                                   (int)n0, (int)n1, mixb);
    gather_kernel<<<gather_grid, 256, 0, stream>>>(vectors, senders, edge_sorted,
                                                   offsets, mtab, cgbuf, mixb,
                                                   (int)n0, (int)n1, out);
  }

  node_out_kernel<<<NN*16/256, 256, 0, stream>>>(node_feats, species,
                                                 Wd0, Wd1, Wd2, Wsk0, Wsk1, Wsk2,
                                                 out, out);
}

// Round 4
// 946.638 us; speedup vs baseline: 7.6318x; 1.0439x over previous
//
#include <hip/hip_runtime.h>
#include <math.h>

#define NN 32768
#define NE 524288

__device__ __forceinline__ float siluf(float x){
  return x * __builtin_amdgcn_rcpf(1.0f + __expf(-x));
}

__device__ __forceinline__ unsigned short f2bf(float x){
  unsigned int b = __float_as_uint(x);
  unsigned int r = ((b >> 16) & 1u) + 0x7fffu;
  return (unsigned short)((b + r) >> 16);
}

__device__ const int d_PL1[11] = {0,1,2,0,1,1,2,0,1,2,2};
__device__ const int d_PL2[11] = {0,1,2,1,0,2,1,2,1,0,2};
__device__ const int d_PL3[11] = {0,0,0,1,1,1,1,2,2,2,2};

// ---------------------------------------------------------------------------
// CG init (1/PATH_NORM folded). All paths have even l1+l2+l3 -> real part.
// ---------------------------------------------------------------------------
__device__ double factd(int n){ double r=1.0; for(int i=2;i<=n;++i) r*=(double)i; return r; }

__device__ double su2_elem(int l1,int l2,int l3,int m1,int m2){
  int m3=m1+m2;
  if (m3 < -l3 || m3 > l3) return 0.0;
  double pref = sqrt((double)(2*l3+1)*factd(l3+l1-l2)*factd(l3-l1+l2)*factd(l1+l2-l3)/factd(l1+l2+l3+1));
  pref *= sqrt(factd(l3+m3)*factd(l3-m3)*factd(l1-m1)*factd(l1+m1)*factd(l2-m2)*factd(l2+m2));
  double s=0.0;
  for (int k=0;k<=l1+l2-l3;++k){
    int t1=l1+l2-l3-k, t2=l1-m1-k, t3=l2+m2-k, t4=l3-l2+m1+k, t5=l3-l1-m2+k;
    if (t1<0||t2<0||t3<0||t4<0||t5<0) continue;
    double d = factd(k)*factd(t1)*factd(t2)*factd(t3)*factd(t4)*factd(t5);
    s += ((k&1)? -1.0:1.0)/d;
  }
  return pref*s;
}

__device__ void q_elem(int l,int a,int i,double& re,double& im){
  re=0.0; im=0.0;
  const double is2 = 0.7071067811865476;
  int m = a - l;
  if (m==0){ if (i==l) re=1.0; return; }
  if (m>0){
    if (i==l+m)      re = (m&1)? -is2: is2;
    else if (i==l-m) re = is2;
  } else {
    int mm=-m;
    if (i==l-mm)      im = is2;
    else if (i==l+mm) im = (mm&1)? is2 : -is2;
  }
}

__global__ void cg_kernel(float* __restrict__ cgout){
  int p = blockIdx.x;
  int t = threadIdx.x;
  if (t >= 125) return;
  int a = t/25, b = (t/5)%5, c = t%5;
  int l1=d_PL1[p], l2=d_PL2[p], l3=d_PL3[p];
  int n1=2*l1+1, n2=2*l2+1, n3=2*l3+1;
  float outv = 0.0f;
  if (a<n1 && b<n2 && c<n3){
    double acc = 0.0;
    for (int i=0;i<n1;++i)
      for (int j=0;j<n2;++j){
        int m1=i-l1, m2=j-l2;
        int m3=m1+m2;
        if (m3 < -l3 || m3 > l3) continue;
        double cv = su2_elem(l1,l2,l3,m1,m2);
        if (cv==0.0) continue;
        int k = m3 + l3;
        double a1r,a1i,a2r,a2i,a3r,a3i;
        q_elem(l1,a,i,a1r,a1i);
        q_elem(l2,b,j,a2r,a2i);
        q_elem(l3,c,k,a3r,a3i);
        double re = (a1r*a2r - a1i*a2i)*a3r + (a1r*a2i + a1i*a2r)*a3i;
        acc += cv*re;
      }
    double invn = (l3==0)? 0.5773502691896258 : 0.5;
    outv = (float)(acc*invn);
  }
  cgout[p*125 + (a*5+b)*5 + c] = outv;
}

// ---------------------------------------------------------------------------
// Node up-projection (scaled 0.25)
// ---------------------------------------------------------------------------
__global__ __launch_bounds__(256) void node_up_kernel(
    const float* __restrict__ nf,
    const float* __restrict__ W0,
    const float* __restrict__ W1,
    const float* __restrict__ W2,
    float* __restrict__ mtab)
{
  int gidx = blockIdx.x*256 + threadIdx.x;
  if (gidx >= NN*144) return;
  int n = gidx/144;
  int col = gidx - n*144;
  const float* f = nf + (size_t)n*144;
  float acc = 0.f;
  if (col < 16){
    int o = col;
    #pragma unroll
    for (int c=0;c<16;++c) acc += f[c]*W0[c*16+o];
  } else if (col < 64){
    int idx = col-16;
    int o = idx/3, i = idx - o*3;
    #pragma unroll
    for (int c=0;c<16;++c) acc += f[16+c*3+i]*W1[c*16+o];
  } else {
    int idx = col-64;
    int o = idx/5, i = idx - o*5;
    #pragma unroll
    for (int c=0;c<16;++c) acc += f[64+c*5+i]*W2[c*16+o];
  }
  mtab[gidx] = 0.25f*acc;
}

// ---------------------------------------------------------------------------
// CSR build
// ---------------------------------------------------------------------------
__global__ __launch_bounds__(256) void hist_kernel(
    const int* __restrict__ recv, int* __restrict__ counts)
{
  int e = blockIdx.x*256 + threadIdx.x;
  if (e < NE) atomicAdd(&counts[recv[e]], 1);
}

__global__ __launch_bounds__(1024) void scan_kernel(
    const int* __restrict__ counts, int* __restrict__ offsets)
{
  __shared__ int part[1024];
  int t = threadIdx.x;
  int local[32];
  int s = 0;
  #pragma unroll
  for (int i=0;i<32;++i){ local[i]=counts[t*32+i]; s+=local[i]; }
  part[t]=s;
  __syncthreads();
  for (int off=1; off<1024; off<<=1){
    int v = (t>=off)? part[t-off] : 0;
    __syncthreads();
    part[t] += v;
    __syncthreads();
  }
  int run = part[t] - s;
  #pragma unroll
  for (int i=0;i<32;++i){ offsets[t*32+i]=run; run+=local[i]; }
  if (t==1023) offsets[NN]=run;
}

__global__ __launch_bounds__(256) void scatter_kernel(
    const int* __restrict__ recv, const int* __restrict__ offsets,
    int* __restrict__ cursor, int* __restrict__ edge_sorted)
{
  int e = blockIdx.x*256 + threadIdx.x;
  if (e < NE){
    int r = recv[e];
    int pos = atomicAdd(&cursor[r], 1);
    edge_sorted[offsets[r] + pos] = e;
  }
}

// chunk boundaries: nb[i] = first node of chunk i; chunk i covers edges
// approx [NE*i/NC, NE*(i+1)/NC)
__global__ __launch_bounds__(256) void find_bounds_kernel(
    const int* __restrict__ offsets, int* __restrict__ nb, int NC)
{
  int n = blockIdx.x*256 + threadIdx.x;
  if (n == 0){ nb[0] = 0; nb[NC] = NN; }
  if (n >= NN) return;
  int o0 = offsets[n], o1 = offsets[n+1];
  for (int i=1; i<NC; ++i){
    long long Ti = (long long)NE*i/NC;
    if (o0 <= Ti && Ti < o1) nb[i] = n+1;
  }
}

// ---------------------------------------------------------------------------
// A: fused radial MLP + mix over sorted slots of chunk ci; mix -> bf16 rows.
// ---------------------------------------------------------------------------
__global__ __launch_bounds__(256) void edge_mix_kernel(
    const float* __restrict__ vectors,
    const int* __restrict__ edge_sorted,
    const int* __restrict__ offsets,
    const int* __restrict__ nb,
    const float* __restrict__ Wm0,
    const float* __restrict__ Wm1,
    const float* __restrict__ Wm2,
    int ci,
    unsigned short* __restrict__ mixb)
{
  int sbase = offsets[nb[ci]];
  int send  = offsets[nb[ci+1]];
  int t = blockIdx.x*256 + threadIdx.x;
  int s = sbase + t;
  if (s >= send) return;
  int e = edge_sorted[s];

  float vx = vectors[(size_t)e*3+0];
  float vy = vectors[(size_t)e*3+1];
  float vz = vectors[(size_t)e*3+2];
  float r = sqrtf(vx*vx + vy*vy + vz*vz);
  float safe = (r > 1e-9f) ? r : 1.0f;
  float inv_safe = 1.0f/safe;

  const float PIf = 3.14159265358979f;
  float xc = fminf(r*0.25f, 1.0f);
  float s1 = __sinf(PIf*xc);
  float c1 = __cosf(PIf*xc);
  float env = 0.5f*(c1 + 1.0f);
  float pref = 0.70710678118f * env * inv_safe;
  float rb[8];
  {
    float sk=s1, ck=c1;
    rb[0]=pref*sk;
    #pragma unroll
    for (int k=1;k<8;++k){
      float sn = sk*c1 + ck*s1;
      float cn = ck*c1 - sk*s1;
      sk=sn; ck=cn;
      rb[k]=pref*sk;
    }
  }

  float h[64];
  #pragma unroll
  for (int o=0;o<64;++o) h[o]=0.f;
  #pragma unroll
  for (int i=0;i<8;++i){
    float ri = rb[i];
    #pragma unroll
    for (int o=0;o<64;++o) h[o] += ri*Wm0[i*64+o];
  }
  #pragma unroll
  for (int o=0;o<64;++o) h[o] = siluf(h[o]*0.3535533906f);

  float h2[64];
  #pragma unroll 1
  for (int oc=0;oc<4;++oc){
    float acc[16];
    #pragma unroll
    for (int c=0;c<16;++c) acc[c]=0.f;
    #pragma unroll
    for (int i=0;i<64;++i){
      float hi = h[i];
      #pragma unroll
      for (int c=0;c<16;++c) acc[c] += hi*Wm1[i*64+oc*16+c];
    }
    #pragma unroll
    for (int c=0;c<16;++c) h2[oc*16+c] = siluf(acc[c]*0.125f);
  }

  float scale = (r == 0.0f) ? 0.0f : 0.125f;
  unsigned short* mrow = mixb + (size_t)t*176;   // t == s - sbase
  #pragma unroll 1
  for (int oc=0;oc<11;++oc){
    float acc[16];
    #pragma unroll
    for (int c=0;c<16;++c) acc[c]=0.f;
    #pragma unroll
    for (int i=0;i<64;++i){
      float hi = h2[i];
      #pragma unroll
      for (int c=0;c<16;++c) acc[c] += hi*Wm2[i*176+oc*16+c];
    }
    unsigned int u[8];
    #pragma unroll
    for (int w=0;w<8;++w){
      u[w] = (unsigned int)f2bf(acc[2*w]*scale) |
             ((unsigned int)f2bf(acc[2*w+1]*scale) << 16);
    }
    uint4* dst = (uint4*)(mrow + oc*16);
    dst[0] = make_uint4(u[0],u[1],u[2],u[3]);
    dst[1] = make_uint4(u[4],u[5],u[6],u[7]);
  }
}

// ---------------------------------------------------------------------------
// B: tensor-product + gather; thread per (node, channel-pair).
// ---------------------------------------------------------------------------
template<int PIDX,int L1,int L2,int L3>
__device__ __forceinline__ void do_path2(
    const float* __restrict__ cgtab,
    const unsigned short* __restrict__ mrow,
    int c0,
    const float (&y1)[3], const float (&y2)[5],
    const float (&xa0)[2], const float (&xa1)[2][3], const float (&xa2)[2][5],
    float (&msg0)[2], float (&msg1)[2][3], float (&msg2)[2][5])
{
  constexpr int d1=2*L1+1, d2=2*L2+1, d3=2*L3+1;
  const float* cgp = cgtab + PIDX*125;

  float yv[d2];
  if constexpr (L2==0){ yv[0]=1.0f; }
  else if constexpr (L2==1){ yv[0]=y1[0]; yv[1]=y1[1]; yv[2]=y1[2]; }
  else {
    #pragma unroll
    for (int j=0;j<5;++j) yv[j]=y2[j];
  }

  float M[d1][d3];
  #pragma unroll
  for (int iu=0;iu<d1;++iu){
    #pragma unroll
    for (int k=0;k<d3;++k){
      float acc = 0.f;
      #pragma unroll
      for (int j=0;j<d2;++j) acc += yv[j]*cgp[(iu*5+j)*5+k];
      M[iu][k]=acc;
    }
  }

  unsigned int u = *(const unsigned int*)(mrow + PIDX*16 + c0);
  float mx0 = __uint_as_float(u << 16);
  float mx1 = __uint_as_float(u & 0xffff0000u);

  #pragma unroll
  for (int ch=0; ch<2; ++ch){
    float mx = (ch==0)? mx0 : mx1;
    #pragma unroll
    for (int k=0;k<d3;++k){
      float t = 0.f;
      #pragma unroll
      for (int iu=0;iu<d1;++iu){
        float xv = (L1==0)? xa0[ch] : (L1==1? xa1[ch][iu] : xa2[ch][iu]);
        t += xv*M[iu][k];
      }
      if constexpr (L3==0)      msg0[ch]    += mx*t;
      else if constexpr (L3==1) msg1[ch][k] += mx*t;
      else                      msg2[ch][k] += mx*t;
    }
  }
}

__global__ __launch_bounds__(256) void gather_kernel(
    const float* __restrict__ vectors,
    const int* __restrict__ senders,
    const int* __restrict__ edge_sorted,
    const int* __restrict__ offsets,
    const int* __restrict__ nb,
    const float* __restrict__ mtab,
    const float* __restrict__ cgtab,
    const unsigned short* __restrict__ mixb,
    int ci,
    float* __restrict__ out)
{
  int t = blockIdx.x*256 + threadIdx.x;
  int n = t >> 3;
  if (n >= NN) return;
  int nlo = nb[ci], nhi = nb[ci+1];
  if (n < nlo || n >= nhi) return;
  int c0 = (t & 7)*2;
  int cbase = offsets[nlo];
  int j0 = offsets[n];
  int j1 = offsets[n+1];

  float msg0[2];
  float msg1[2][3];
  float msg2[2][5];
  #pragma unroll
  for (int ch=0;ch<2;++ch){
    msg0[ch]=0.f;
    #pragma unroll
    for (int i=0;i<3;++i) msg1[ch][i]=0.f;
    #pragma unroll
    for (int i=0;i<5;++i) msg2[ch][i]=0.f;
  }

  const float SQ3  = 1.73205080757f;
  const float SQ15 = 3.87298334621f;

  for (int j=j0; j<j1; ++j){
    int e = edge_sorted[j];
    float vx = vectors[(size_t)e*3+0];
    float vy = vectors[(size_t)e*3+1];
    float vz = vectors[(size_t)e*3+2];
    float r = sqrtf(vx*vx + vy*vy + vz*vz);
    float safe = (r > 1e-9f) ? r : 1.0f;
    float inv_safe = 1.0f/safe;
    float ux=vx*inv_safe, uy=vy*inv_safe, uz=vz*inv_safe;

    float y1[3] = { SQ3*uy, SQ3*uz, SQ3*ux };
    float y2[5] = { SQ15*ux*uy, SQ15*uy*uz, 1.11803398875f*(3.f*uz*uz-1.f),
                    SQ15*ux*uz, 1.93649167310f*(ux*ux-uy*uy) };

    const float* xp = mtab + (size_t)senders[e]*144;
    float xa0[2];
    float xa1[2][3];
    float xa2[2][5];
    #pragma unroll
    for (int ch=0;ch<2;++ch) xa0[ch] = xp[c0+ch];
    #pragma unroll
    for (int ch=0;ch<2;++ch){
      #pragma unroll
      for (int i=0;i<3;++i) xa1[ch][i] = xp[16 + (c0+ch)*3 + i];
    }
    #pragma unroll
    for (int ch=0;ch<2;++ch){
      #pragma unroll
      for (int i=0;i<5;++i) xa2[ch][i] = xp[64 + (c0+ch)*5 + i];
    }

    const unsigned short* mrow = mixb + (size_t)(j - cbase)*176;

    do_path2< 0,0,0,0>(cgtab,mrow,c0,y1,y2,xa0,xa1,xa2,msg0,msg1,msg2);
    do_path2< 1,1,1,0>(cgtab,mrow,c0,y1,y2,xa0,xa1,xa2,msg0,msg1,msg2);
    do_path2< 2,2,2,0>(cgtab,mrow,c0,y1,y2,xa0,xa1,xa2,msg0,msg1,msg2);
    do_path2< 3,0,1,1>(cgtab,mrow,c0,y1,y2,xa0,xa1,xa2,msg0,msg1,msg2);
    do_path2< 4,1,0,1>(cgtab,mrow,c0,y1,y2,xa0,xa1,xa2,msg0,msg1,msg2);
    do_path2< 5,1,2,1>(cgtab,mrow,c0,y1,y2,xa0,xa1,xa2,msg0,msg1,msg2);
    do_path2< 6,2,1,1>(cgtab,mrow,c0,y1,y2,xa0,xa1,xa2,msg0,msg1,msg2);
    do_path2< 7,0,2,2>(cgtab,mrow,c0,y1,y2,xa0,xa1,xa2,msg0,msg1,msg2);
    do_path2< 8,1,1,2>(cgtab,mrow,c0,y1,y2,xa0,xa1,xa2,msg0,msg1,msg2);
    do_path2< 9,2,0,2>(cgtab,mrow,c0,y1,y2,xa0,xa1,xa2,msg0,msg1,msg2);
    do_path2<10,2,2,2>(cgtab,mrow,c0,y1,y2,xa0,xa1,xa2,msg0,msg1,msg2);
  }

  float* on = out + (size_t)n*144;
  #pragma unroll
  for (int ch=0;ch<2;++ch) on[c0+ch] = msg0[ch];
  #pragma unroll
  for (int ch=0;ch<2;++ch){
    #pragma unroll
    for (int i=0;i<3;++i) on[16 + (c0+ch)*3 + i] = msg1[ch][i];
  }
  #pragma unroll
  for (int ch=0;ch<2;++ch){
    #pragma unroll
    for (int i=0;i<5;++i) on[64 + (c0+ch)*5 + i] = msg2[ch][i];
  }
}

// ---------------------------------------------------------------------------
// Final node update, in-place on out.
// ---------------------------------------------------------------------------
__global__ __launch_bounds__(256) void node_out_kernel(
    const float* __restrict__ nf,
    const int* __restrict__ species,
    const float* __restrict__ Wd0,
    const float* __restrict__ Wd1,
    const float* __restrict__ Wd2,
    const float* __restrict__ Wsk0,
    const float* __restrict__ Wsk1,
    const float* __restrict__ Wsk2,
    const float* agg,
    float* out)
{
  int t = blockIdx.x*256 + threadIdx.x;
  int n = t >> 4;
  int o = t & 15;
  if (n >= NN) return;
  const float* an = agg + (size_t)n*144;
  const float* f  = nf  + (size_t)n*144;
  int sp = species[n];
  const float* wk0 = Wsk0 + sp*768;
  const float* wk1 = Wsk1 + sp*256;
  const float* wk2 = Wsk2 + sp*256;

  float sa0=0,sa1=0,sa2=0, sf0=0,sf1=0,sf2=0;
  #pragma unroll
  for (int c=0;c<16;++c){
    float a = an[c], ff = f[c];
    sa0 += a*Wd0[c*48+o];
    sa1 += a*Wd0[c*48+16+o];
    sa2 += a*Wd0[c*48+32+o];
    sf0 += ff*wk0[c*48+o];
    sf1 += ff*wk0[c*48+16+o];
    sf2 += ff*wk0[c*48+32+o];
  }
  float s0 = 0.0625f*sa0 + 0.25f*sf0;
  float s1 = 0.0625f*sa1 + 0.25f*sf1;
  float s2 = 0.0625f*sa2 + 0.25f*sf2;
  float scv = siluf(s0);
  float g1  = siluf(s1);
  float g2  = siluf(s2);

  float v[3];
  #pragma unroll
  for (int i=0;i<3;++i){
    float av=0, fv=0;
    #pragma unroll
    for (int c=0;c<16;++c){
      av += an[16+c*3+i]*Wd1[c*16+o];
      fv += f[16+c*3+i]*wk1[c*16+o];
    }
    v[i] = (0.0625f*av + 0.25f*fv)*g1;
  }
  float q[5];
  #pragma unroll
  for (int i=0;i<5;++i){
    float av=0, fv=0;
    #pragma unroll
    for (int c=0;c<16;++c){
      av += an[64+c*5+i]*Wd2[c*16+o];
      fv += f[64+c*5+i]*wk2[c*16+o];
    }
    q[i] = (0.0625f*av + 0.25f*fv)*g2;
  }

  float* on = out + (size_t)n*144;
  on[o] = scv;
  #pragma unroll
  for (int i=0;i<3;++i) on[16+o*3+i] = v[i];
  #pragma unroll
  for (int i=0;i<5;++i) on[64+o*5+i] = q[i];
}

// ---------------------------------------------------------------------------
extern "C" void kernel_launch(void* const* d_in, const int* in_sizes, int n_in,
                              void* d_out, int out_size, void* d_ws, size_t ws_size,
                              hipStream_t stream)
{
  const float* vectors    = (const float*)d_in[0];
  const float* node_feats = (const float*)d_in[1];
  const int*   species    = (const int*)d_in[2];
  const int*   senders    = (const int*)d_in[3];
  const int*   receivers  = (const int*)d_in[4];
  const float* W_up0 = (const float*)d_in[5];
  const float* W_up1 = (const float*)d_in[6];
  const float* W_up2 = (const float*)d_in[7];
  const float* Wm0   = (const float*)d_in[8];
  const float* Wm1   = (const float*)d_in[9];
  const float* Wm2   = (const float*)d_in[10];
  const float* Wd0   = (const float*)d_in[11];
  const float* Wd1   = (const float*)d_in[12];
  const float* Wd2   = (const float*)d_in[13];
  const float* Wsk0  = (const float*)d_in[14];
  const float* Wsk1  = (const float*)d_in[15];
  const float* Wsk2  = (const float*)d_in[16];
  float* out = (float*)d_out;
  float* ws  = (float*)d_ws;

  // ws layout (float units):
  // [cg 2048][mtab NN*144][counts NN][cursor NN][offsets NN+64][edge_sorted NE][nb 16][mixb bf16 ...]
  float* cgbuf = ws;
  float* mtab  = ws + 2048;
  int* counts      = (int*)(ws + 2048 + (size_t)NN*144);
  int* cursor      = counts + NN;
  int* offsets     = cursor + NN;
  int* edge_sorted = offsets + NN + 64;
  int* nb          = edge_sorted + NE;
  unsigned short* mixb = (unsigned short*)(nb + 16);

  size_t fixed_f = 2048 + (size_t)NN*144 + NN + NN + (NN+64) + NE + 16;
  size_t ws_f = ws_size/4;
  long long cap_rows = (ws_f > fixed_f) ? (long long)((ws_f - fixed_f)/88) : 0; // 176 bf16 = 88 f
  long long capm = cap_rows - 4096;
  if (capm < 16384) capm = 16384;  // assume ws is at least ~12 MB past fixed
  int NC = (int)((NE + capm - 1)/capm);
  if (NC < 1) NC = 1;
  if (NC > 15) NC = 15;

  hipMemsetAsync(counts, 0, 2*(size_t)NN*sizeof(int), stream);
  cg_kernel<<<11, 128, 0, stream>>>(cgbuf);
  node_up_kernel<<<(NN*144)/256, 256, 0, stream>>>(node_feats, W_up0, W_up1, W_up2, mtab);
  hist_kernel<<<NE/256, 256, 0, stream>>>(receivers, counts);
  scan_kernel<<<1, 1024, 0, stream>>>(counts, offsets);
  scatter_kernel<<<NE/256, 256, 0, stream>>>(receivers, offsets, cursor, edge_sorted);
  find_bounds_kernel<<<NN/256, 256, 0, stream>>>(offsets, nb, NC);

  long long chunk_edges_max = NE/NC + 4096;
  int gA = (int)((chunk_edges_max + 255)/256);
  int gB = NN*8/256;
  for (int ci = 0; ci < NC; ++ci){
    edge_mix_kernel<<<gA, 256, 0, stream>>>(vectors, edge_sorted, offsets, nb,
                                            Wm0, Wm1, Wm2, ci, mixb);
    gather_kernel<<<gB, 256, 0, stream>>>(vectors, senders, edge_sorted, offsets,
                                          nb, mtab, cgbuf, mixb, ci, out);
  }

  node_out_kernel<<<NN*16/256, 256, 0, stream>>>(node_feats, species,
                                                 Wd0, Wd1, Wd2, Wsk0, Wsk1, Wsk2,
                                                 out, out);
}

// Round 5
// 587.179 us; speedup vs baseline: 12.3039x; 1.6122x over previous
//
#include <hip/hip_runtime.h>
#include <math.h>

#define NN 32768
#define NE 524288

typedef __attribute__((ext_vector_type(8))) short short8v;
typedef __attribute__((ext_vector_type(4))) float f32x4;

__device__ __forceinline__ float siluf(float x){
  return x * __builtin_amdgcn_rcpf(1.0f + __expf(-x));
}

__device__ __forceinline__ unsigned short f2bf(float x){
  unsigned int b = __float_as_uint(x);
  unsigned int r = ((b >> 16) & 1u) + 0x7fffu;
  return (unsigned short)((b + r) >> 16);
}

__device__ const int d_PL1[11] = {0,1,2,0,1,1,2,0,1,2,2};
__device__ const int d_PL2[11] = {0,1,2,1,0,2,1,2,1,0,2};
__device__ const int d_PL3[11] = {0,0,0,1,1,1,1,2,2,2,2};

// ---------------------------------------------------------------------------
// CG init (1/PATH_NORM folded). All paths have even l1+l2+l3 -> real part.
// ---------------------------------------------------------------------------
__device__ double factd(int n){ double r=1.0; for(int i=2;i<=n;++i) r*=(double)i; return r; }

__device__ double su2_elem(int l1,int l2,int l3,int m1,int m2){
  int m3=m1+m2;
  if (m3 < -l3 || m3 > l3) return 0.0;
  double pref = sqrt((double)(2*l3+1)*factd(l3+l1-l2)*factd(l3-l1+l2)*factd(l1+l2-l3)/factd(l1+l2+l3+1));
  pref *= sqrt(factd(l3+m3)*factd(l3-m3)*factd(l1-m1)*factd(l1+m1)*factd(l2-m2)*factd(l2+m2));
  double s=0.0;
  for (int k=0;k<=l1+l2-l3;++k){
    int t1=l1+l2-l3-k, t2=l1-m1-k, t3=l2+m2-k, t4=l3-l2+m1+k, t5=l3-l1-m2+k;
    if (t1<0||t2<0||t3<0||t4<0||t5<0) continue;
    double d = factd(k)*factd(t1)*factd(t2)*factd(t3)*factd(t4)*factd(t5);
    s += ((k&1)? -1.0:1.0)/d;
  }
  return pref*s;
}

__device__ void q_elem(int l,int a,int i,double& re,double& im){
  re=0.0; im=0.0;
  const double is2 = 0.7071067811865476;
  int m = a - l;
  if (m==0){ if (i==l) re=1.0; return; }
  if (m>0){
    if (i==l+m)      re = (m&1)? -is2: is2;
    else if (i==l-m) re = is2;
  } else {
    int mm=-m;
    if (i==l-mm)      im = is2;
    else if (i==l+mm) im = (mm&1)? is2 : -is2;
  }
}

__global__ void cg_kernel(float* __restrict__ cgout){
  int p = blockIdx.x;
  int t = threadIdx.x;
  if (t >= 125) return;
  int a = t/25, b = (t/5)%5, c = t%5;
  int l1=d_PL1[p], l2=d_PL2[p], l3=d_PL3[p];
  int n1=2*l1+1, n2=2*l2+1, n3=2*l3+1;
  float outv = 0.0f;
  if (a<n1 && b<n2 && c<n3){
    double acc = 0.0;
    for (int i=0;i<n1;++i)
      for (int j=0;j<n2;++j){
        int m1=i-l1, m2=j-l2;
        int m3=m1+m2;
        if (m3 < -l3 || m3 > l3) continue;
        double cv = su2_elem(l1,l2,l3,m1,m2);
        if (cv==0.0) continue;
        int k = m3 + l3;
        double a1r,a1i,a2r,a2i,a3r,a3i;
        q_elem(l1,a,i,a1r,a1i);
        q_elem(l2,b,j,a2r,a2i);
        q_elem(l3,c,k,a3r,a3i);
        double re = (a1r*a2r - a1i*a2i)*a3r + (a1r*a2i + a1i*a2r)*a3i;
        acc += cv*re;
      }
    double invn = (l3==0)? 0.5773502691896258 : 0.5;
    outv = (float)(acc*invn);
  }
  cgout[p*125 + (a*5+b)*5 + c] = outv;
}

// ---------------------------------------------------------------------------
// Node up-projection (scaled 0.25)
// ---------------------------------------------------------------------------
__global__ __launch_bounds__(256) void node_up_kernel(
    const float* __restrict__ nf,
    const float* __restrict__ W0,
    const float* __restrict__ W1,
    const float* __restrict__ W2,
    float* __restrict__ mtab)
{
  int gidx = blockIdx.x*256 + threadIdx.x;
  if (gidx >= NN*144) return;
  int n = gidx/144;
  int col = gidx - n*144;
  const float* f = nf + (size_t)n*144;
  float acc = 0.f;
  if (col < 16){
    int o = col;
    #pragma unroll
    for (int c=0;c<16;++c) acc += f[c]*W0[c*16+o];
  } else if (col < 64){
    int idx = col-16;
    int o = idx/3, i = idx - o*3;
    #pragma unroll
    for (int c=0;c<16;++c) acc += f[16+c*3+i]*W1[c*16+o];
  } else {
    int idx = col-64;
    int o = idx/5, i = idx - o*5;
    #pragma unroll
    for (int c=0;c<16;++c) acc += f[64+c*5+i]*W2[c*16+o];
  }
  mtab[gidx] = 0.25f*acc;
}

// ---------------------------------------------------------------------------
// CSR build
// ---------------------------------------------------------------------------
__global__ __launch_bounds__(256) void hist_kernel(
    const int* __restrict__ recv, int* __restrict__ counts)
{
  int e = blockIdx.x*256 + threadIdx.x;
  if (e < NE) atomicAdd(&counts[recv[e]], 1);
}

__global__ __launch_bounds__(1024) void scan_kernel(
    const int* __restrict__ counts, int* __restrict__ offsets)
{
  __shared__ int part[1024];
  int t = threadIdx.x;
  int local[32];
  int s = 0;
  #pragma unroll
  for (int i=0;i<32;++i){ local[i]=counts[t*32+i]; s+=local[i]; }
  part[t]=s;
  __syncthreads();
  for (int off=1; off<1024; off<<=1){
    int v = (t>=off)? part[t-off] : 0;
    __syncthreads();
    part[t] += v;
    __syncthreads();
  }
  int run = part[t] - s;
  #pragma unroll
  for (int i=0;i<32;++i){ offsets[t*32+i]=run; run+=local[i]; }
  if (t==1023) offsets[NN]=run;
}

__global__ __launch_bounds__(256) void scatter_kernel(
    const int* __restrict__ recv, const int* __restrict__ offsets,
    int* __restrict__ cursor, int* __restrict__ edge_sorted)
{
  int e = blockIdx.x*256 + threadIdx.x;
  if (e < NE){
    int r = recv[e];
    int pos = atomicAdd(&cursor[r], 1);
    edge_sorted[offsets[r] + pos] = e;
  }
}

__global__ __launch_bounds__(256) void find_bounds_kernel(
    const int* __restrict__ offsets, int* __restrict__ nb, int NC)
{
  int n = blockIdx.x*256 + threadIdx.x;
  if (n == 0){ nb[0] = 0; nb[NC] = NN; }
  if (n >= NN) return;
  int o0 = offsets[n], o1 = offsets[n+1];
  for (int i=1; i<NC; ++i){
    long long Ti = (long long)NE*i/NC;
    if (o0 <= Ti && Ti < o1) nb[i] = n+1;
  }
}

// ---------------------------------------------------------------------------
// Pack Wm1/Wm2 into bf16 B-fragment order:
// Wp[((ni*2+ks)*64 + lane)*8 + j] = bf16( W[k*LD + ni*16 + (lane&15)] ),
// k = ks*32 + (lane>>4)*8 + j.   (same k-slot convention as the A side)
// ---------------------------------------------------------------------------
__global__ __launch_bounds__(256) void pack_w_kernel(
    const float* __restrict__ Wm1, const float* __restrict__ Wm2,
    unsigned short* __restrict__ Wm1p, unsigned short* __restrict__ Wm2p)
{
  int t = blockIdx.x*256 + threadIdx.x;
  if (t < 4096){
    int j = t & 7, lane = (t>>3)&63, ks = (t>>9)&1, ni = t>>10;
    int k = ks*32 + (lane>>4)*8 + j;
    int col = ni*16 + (lane&15);
    Wm1p[t] = f2bf(Wm1[k*64+col]);
  }
  int t2 = t - 4096;
  if (t2 >= 0 && t2 < 11264){
    int j = t2 & 7, lane = (t2>>3)&63, ks = (t2>>9)&1, ni = t2>>10;
    int k = ks*32 + (lane>>4)*8 + j;
    int col = ni*16 + (lane&15);
    Wm2p[t2] = f2bf(Wm2[k*176+col]);
  }
}

// ---------------------------------------------------------------------------
// Edge MLP + mix with MFMA. One wave = 64 edges. 256 thr = 4 independent waves.
// LDS per wave: h/h2 buffer [8 kchunks][64 rows][8 bf16] = 8KB (reused), s[64].
// mixb output: plane layout [path ni][slot][16 ch] bf16.
// ---------------------------------------------------------------------------
__global__ __launch_bounds__(256) void edge_mix_kernel(
    const float* __restrict__ vectors,
    const int* __restrict__ edge_sorted,
    const int* __restrict__ offsets,
    const int* __restrict__ nb,
    const float* __restrict__ Wm0,
    const unsigned short* __restrict__ Wm1p,
    const unsigned short* __restrict__ Wm2p,
    int ci, int plane_stride,
    unsigned short* __restrict__ mixb)
{
  __shared__ unsigned short lds_h[4][8*64*8];
  __shared__ float lds_s[4][64];

  int sbase = offsets[nb[ci]];
  int nE = offsets[nb[ci+1]] - sbase;
  int tid = threadIdx.x;
  int wid = tid >> 6;
  int lane = tid & 63;
  int g = lane >> 4;
  int l15 = lane & 15;
  int wb = blockIdx.x*256 + wid*64;       // chunk-local slot base of this wave
  int slot = wb + lane;

  // ---- phase 1: per-lane radial basis + layer 1 (f32, scalar weights) ----
  float vx=0.f, vy=0.f, vz=0.f;
  if (slot < nE){
    int e = edge_sorted[sbase + slot];
    vx = vectors[(size_t)e*3+0];
    vy = vectors[(size_t)e*3+1];
    vz = vectors[(size_t)e*3+2];
  }
  float r = sqrtf(vx*vx + vy*vy + vz*vz);
  float safe = (r > 1e-9f) ? r : 1.0f;
  float inv_safe = 1.0f/safe;

  const float PIf = 3.14159265358979f;
  float xc = fminf(r*0.25f, 1.0f);
  float s1 = __sinf(PIf*xc);
  float c1 = __cosf(PIf*xc);
  float env = 0.5f*(c1 + 1.0f);
  float pref = 0.70710678118f * env * inv_safe;
  float rb[8];
  {
    float sk=s1, ck=c1;
    rb[0]=pref*sk;
    #pragma unroll
    for (int k=1;k<8;++k){
      float sn = sk*c1 + ck*s1;
      float cn = ck*c1 - sk*s1;
      sk=sn; ck=cn;
      rb[k]=pref*sk;
    }
  }

  float h[64];
  #pragma unroll
  for (int o=0;o<64;++o) h[o]=0.f;
  #pragma unroll
  for (int i=0;i<8;++i){
    float ri = rb[i];
    #pragma unroll
    for (int o=0;o<64;++o) h[o] += ri*Wm0[i*64+o];
  }

  unsigned short* Lh = lds_h[wid];
  // write h as bf16 into [kchunk][row=lane][8]; conflict-free (lanes contiguous)
  #pragma unroll
  for (int c=0;c<8;++c){
    union { unsigned int u[4]; short8v v; } pk;
    #pragma unroll
    for (int w=0;w<4;++w){
      float a0 = siluf(h[c*8+2*w  ]*0.3535533906f);
      float a1 = siluf(h[c*8+2*w+1]*0.3535533906f);
      pk.u[w] = (unsigned int)f2bf(a0) | ((unsigned int)f2bf(a1) << 16);
    }
    *(short8v*)(Lh + ((size_t)(c*64 + lane))*8) = pk.v;
  }
  lds_s[wid][lane] = (r == 0.0f) ? 0.0f : 0.125f;

  __syncthreads();

  // ---- phase 2: h2 = silu( (h @ Wm1) / 8 ), via MFMA; overwrite Lh with h2 ----
  short8v a[8];
  #pragma unroll
  for (int mi=0;mi<4;++mi){
    #pragma unroll
    for (int ks=0;ks<2;++ks)
      a[mi*2+ks] = *(short8v*)(Lh + ((size_t)((ks*4+g)*64 + mi*16 + l15))*8);
  }
  #pragma unroll 1
  for (int ni=0;ni<4;++ni){
    short8v b0 = *(short8v*)(Wm1p + ((size_t)((ni*2+0)*64 + lane))*8);
    short8v b1 = *(short8v*)(Wm1p + ((size_t)((ni*2+1)*64 + lane))*8);
    int chnk = ni*2 + (l15>>3);
    int cb = l15 & 7;
    #pragma unroll
    for (int mi=0;mi<4;++mi){
      f32x4 acc = {0.f,0.f,0.f,0.f};
      acc = __builtin_amdgcn_mfma_f32_16x16x32_bf16(a[mi*2+0], b0, acc, 0,0,0);
      acc = __builtin_amdgcn_mfma_f32_16x16x32_bf16(a[mi*2+1], b1, acc, 0,0,0);
      #pragma unroll
      for (int reg=0;reg<4;++reg){
        int row = mi*16 + g*4 + reg;
        Lh[((size_t)(chnk*64 + row))*8 + cb] = f2bf(siluf(acc[reg]*0.125f));
      }
    }
  }

  // ---- phase 3: mix = (h2 @ Wm2) * scale, via MFMA; store to mixb planes ----
  short8v a2[8];
  #pragma unroll
  for (int mi=0;mi<4;++mi){
    #pragma unroll
    for (int ks=0;ks<2;++ks)
      a2[mi*2+ks] = *(short8v*)(Lh + ((size_t)((ks*4+g)*64 + mi*16 + l15))*8);
  }
  f32x4 scv[4];
  #pragma unroll
  for (int mi=0;mi<4;++mi)
    scv[mi] = *(f32x4*)(&lds_s[wid][mi*16 + g*4]);

  #pragma unroll 1
  for (int ni=0;ni<11;++ni){
    short8v b0 = *(short8v*)(Wm2p + ((size_t)((ni*2+0)*64 + lane))*8);
    short8v b1 = *(short8v*)(Wm2p + ((size_t)((ni*2+1)*64 + lane))*8);
    #pragma unroll
    for (int mi=0;mi<4;++mi){
      f32x4 acc = {0.f,0.f,0.f,0.f};
      acc = __builtin_amdgcn_mfma_f32_16x16x32_bf16(a2[mi*2+0], b0, acc, 0,0,0);
      acc = __builtin_amdgcn_mfma_f32_16x16x32_bf16(a2[mi*2+1], b1, acc, 0,0,0);
      #pragma unroll
      for (int reg=0;reg<4;++reg){
        int row = mi*16 + g*4 + reg;
        int sl = wb + row;
        if (sl < nE)
          mixb[((size_t)ni*plane_stride + sl)*16 + l15] = f2bf(acc[reg]*scv[mi][reg]);
      }
    }
  }
}

// ---------------------------------------------------------------------------
// Tensor-product + gather; thread per (node, channel-pair). No atomics.
// ---------------------------------------------------------------------------
template<int PIDX,int L1,int L2,int L3>
__device__ __forceinline__ void do_path2(
    const float* __restrict__ cgtab,
    const unsigned short* __restrict__ mixb,
    size_t slot, size_t plane_stride,
    int c0,
    const float (&y1)[3], const float (&y2)[5],
    const float (&xa0)[2], const float (&xa1)[2][3], const float (&xa2)[2][5],
    float (&msg0)[2], float (&msg1)[2][3], float (&msg2)[2][5])
{
  constexpr int d1=2*L1+1, d2=2*L2+1, d3=2*L3+1;
  const float* cgp = cgtab + PIDX*125;

  float yv[d2];
  if constexpr (L2==0){ yv[0]=1.0f; }
  else if constexpr (L2==1){ yv[0]=y1[0]; yv[1]=y1[1]; yv[2]=y1[2]; }
  else {
    #pragma unroll
    for (int j=0;j<5;++j) yv[j]=y2[j];
  }

  float M[d1][d3];
  #pragma unroll
  for (int iu=0;iu<d1;++iu){
    #pragma unroll
    for (int k=0;k<d3;++k){
      float acc = 0.f;
      #pragma unroll
      for (int j=0;j<d2;++j) acc += yv[j]*cgp[(iu*5+j)*5+k];
      M[iu][k]=acc;
    }
  }

  unsigned int u = *(const unsigned int*)(mixb + ((size_t)PIDX*plane_stride + slot)*16 + c0);
  float mx0 = __uint_as_float(u << 16);
  float mx1 = __uint_as_float(u & 0xffff0000u);

  #pragma unroll
  for (int ch=0; ch<2; ++ch){
    float mx = (ch==0)? mx0 : mx1;
    #pragma unroll
    for (int k=0;k<d3;++k){
      float t = 0.f;
      #pragma unroll
      for (int iu=0;iu<d1;++iu){
        float xv = (L1==0)? xa0[ch] : (L1==1? xa1[ch][iu] : xa2[ch][iu]);
        t += xv*M[iu][k];
      }
      if constexpr (L3==0)      msg0[ch]    += mx*t;
      else if constexpr (L3==1) msg1[ch][k] += mx*t;
      else                      msg2[ch][k] += mx*t;
    }
  }
}

__global__ __launch_bounds__(256) void gather_kernel(
    const float* __restrict__ vectors,
    const int* __restrict__ senders,
    const int* __restrict__ edge_sorted,
    const int* __restrict__ offsets,
    const int* __restrict__ nb,
    const float* __restrict__ mtab,
    const float* __restrict__ cgtab,
    const unsigned short* __restrict__ mixb,
    int ci, int plane_stride,
    float* __restrict__ out)
{
  int t = blockIdx.x*256 + threadIdx.x;
  int n = t >> 3;
  if (n >= NN) return;
  int nlo = nb[ci], nhi = nb[ci+1];
  if (n < nlo || n >= nhi) return;
  int c0 = (t & 7)*2;
  int cbase = offsets[nlo];
  int j0 = offsets[n];
  int j1 = offsets[n+1];

  float msg0[2];
  float msg1[2][3];
  float msg2[2][5];
  #pragma unroll
  for (int ch=0;ch<2;++ch){
    msg0[ch]=0.f;
    #pragma unroll
    for (int i=0;i<3;++i) msg1[ch][i]=0.f;
    #pragma unroll
    for (int i=0;i<5;++i) msg2[ch][i]=0.f;
  }

  const float SQ3  = 1.73205080757f;
  const float SQ15 = 3.87298334621f;

  for (int j=j0; j<j1; ++j){
    int e = edge_sorted[j];
    float vx = vectors[(size_t)e*3+0];
    float vy = vectors[(size_t)e*3+1];
    float vz = vectors[(size_t)e*3+2];
    float r = sqrtf(vx*vx + vy*vy + vz*vz);
    float safe = (r > 1e-9f) ? r : 1.0f;
    float inv_safe = 1.0f/safe;
    float ux=vx*inv_safe, uy=vy*inv_safe, uz=vz*inv_safe;

    float y1[3] = { SQ3*uy, SQ3*uz, SQ3*ux };
    float y2[5] = { SQ15*ux*uy, SQ15*uy*uz, 1.11803398875f*(3.f*uz*uz-1.f),
                    SQ15*ux*uz, 1.93649167310f*(ux*ux-uy*uy) };

    const float* xp = mtab + (size_t)senders[e]*144;
    float xa0[2];
    float xa1[2][3];
    float xa2[2][5];
    #pragma unroll
    for (int ch=0;ch<2;++ch) xa0[ch] = xp[c0+ch];
    #pragma unroll
    for (int ch=0;ch<2;++ch){
      #pragma unroll
      for (int i=0;i<3;++i) xa1[ch][i] = xp[16 + (c0+ch)*3 + i];
    }
    #pragma unroll
    for (int ch=0;ch<2;++ch){
      #pragma unroll
      for (int i=0;i<5;++i) xa2[ch][i] = xp[64 + (c0+ch)*5 + i];
    }

    size_t slot = (size_t)(j - cbase);

    do_path2< 0,0,0,0>(cgtab,mixb,slot,plane_stride,c0,y1,y2,xa0,xa1,xa2,msg0,msg1,msg2);
    do_path2< 1,1,1,0>(cgtab,mixb,slot,plane_stride,c0,y1,y2,xa0,xa1,xa2,msg0,msg1,msg2);
    do_path2< 2,2,2,0>(cgtab,mixb,slot,plane_stride,c0,y1,y2,xa0,xa1,xa2,msg0,msg1,msg2);
    do_path2< 3,0,1,1>(cgtab,mixb,slot,plane_stride,c0,y1,y2,xa0,xa1,xa2,msg0,msg1,msg2);
    do_path2< 4,1,0,1>(cgtab,mixb,slot,plane_stride,c0,y1,y2,xa0,xa1,xa2,msg0,msg1,msg2);
    do_path2< 5,1,2,1>(cgtab,mixb,slot,plane_stride,c0,y1,y2,xa0,xa1,xa2,msg0,msg1,msg2);
    do_path2< 6,2,1,1>(cgtab,mixb,slot,plane_stride,c0,y1,y2,xa0,xa1,xa2,msg0,msg1,msg2);
    do_path2< 7,0,2,2>(cgtab,mixb,slot,plane_stride,c0,y1,y2,xa0,xa1,xa2,msg0,msg1,msg2);
    do_path2< 8,1,1,2>(cgtab,mixb,slot,plane_stride,c0,y1,y2,xa0,xa1,xa2,msg0,msg1,msg2);
    do_path2< 9,2,0,2>(cgtab,mixb,slot,plane_stride,c0,y1,y2,xa0,xa1,xa2,msg0,msg1,msg2);
    do_path2<10,2,2,2>(cgtab,mixb,slot,plane_stride,c0,y1,y2,xa0,xa1,xa2,msg0,msg1,msg2);
  }

  float* on = out + (size_t)n*144;
  #pragma unroll
  for (int ch=0;ch<2;++ch) on[c0+ch] = msg0[ch];
  #pragma unroll
  for (int ch=0;ch<2;++ch){
    #pragma unroll
    for (int i=0;i<3;++i) on[16 + (c0+ch)*3 + i] = msg1[ch][i];
  }
  #pragma unroll
  for (int ch=0;ch<2;++ch){
    #pragma unroll
    for (int i=0;i<5;++i) on[64 + (c0+ch)*5 + i] = msg2[ch][i];
  }
}

// ---------------------------------------------------------------------------
// Final node update, in-place on out.
// ---------------------------------------------------------------------------
__global__ __launch_bounds__(256) void node_out_kernel(
    const float* __restrict__ nf,
    const int* __restrict__ species,
    const float* __restrict__ Wd0,
    const float* __restrict__ Wd1,
    const float* __restrict__ Wd2,
    const float* __restrict__ Wsk0,
    const float* __restrict__ Wsk1,
    const float* __restrict__ Wsk2,
    const float* agg,
    float* out)
{
  int t = blockIdx.x*256 + threadIdx.x;
  int n = t >> 4;
  int o = t & 15;
  if (n >= NN) return;
  const float* an = agg + (size_t)n*144;
  const float* f  = nf  + (size_t)n*144;
  int sp = species[n];
  const float* wk0 = Wsk0 + sp*768;
  const float* wk1 = Wsk1 + sp*256;
  const float* wk2 = Wsk2 + sp*256;

  float sa0=0,sa1=0,sa2=0, sf0=0,sf1=0,sf2=0;
  #pragma unroll
  for (int c=0;c<16;++c){
    float a = an[c], ff = f[c];
    sa0 += a*Wd0[c*48+o];
    sa1 += a*Wd0[c*48+16+o];
    sa2 += a*Wd0[c*48+32+o];
    sf0 += ff*wk0[c*48+o];
    sf1 += ff*wk0[c*48+16+o];
    sf2 += ff*wk0[c*48+32+o];
  }
  float s0 = 0.0625f*sa0 + 0.25f*sf0;
  float s1 = 0.0625f*sa1 + 0.25f*sf1;
  float s2 = 0.0625f*sa2 + 0.25f*sf2;
  float scvv = siluf(s0);
  float g1  = siluf(s1);
  float g2  = siluf(s2);

  float v[3];
  #pragma unroll
  for (int i=0;i<3;++i){
    float av=0, fv=0;
    #pragma unroll
    for (int c=0;c<16;++c){
      av += an[16+c*3+i]*Wd1[c*16+o];
      fv += f[16+c*3+i]*wk1[c*16+o];
    }
    v[i] = (0.0625f*av + 0.25f*fv)*g1;
  }
  float q[5];
  #pragma unroll
  for (int i=0;i<5;++i){
    float av=0, fv=0;
    #pragma unroll
    for (int c=0;c<16;++c){
      av += an[64+c*5+i]*Wd2[c*16+o];
      fv += f[64+c*5+i]*wk2[c*16+o];
    }
    q[i] = (0.0625f*av + 0.25f*fv)*g2;
  }

  float* on = out + (size_t)n*144;
  on[o] = scvv;
  #pragma unroll
  for (int i=0;i<3;++i) on[16+o*3+i] = v[i];
  #pragma unroll
  for (int i=0;i<5;++i) on[64+o*5+i] = q[i];
}

// ---------------------------------------------------------------------------
extern "C" void kernel_launch(void* const* d_in, const int* in_sizes, int n_in,
                              void* d_out, int out_size, void* d_ws, size_t ws_size,
                              hipStream_t stream)
{
  const float* vectors    = (const float*)d_in[0];
  const float* node_feats = (const float*)d_in[1];
  const int*   species    = (const int*)d_in[2];
  const int*   senders    = (const int*)d_in[3];
  const int*   receivers  = (const int*)d_in[4];
  const float* W_up0 = (const float*)d_in[5];
  const float* W_up1 = (const float*)d_in[6];
  const float* W_up2 = (const float*)d_in[7];
  const float* Wm0   = (const float*)d_in[8];
  const float* Wm1   = (const float*)d_in[9];
  const float* Wm2   = (const float*)d_in[10];
  const float* Wd0   = (const float*)d_in[11];
  const float* Wd1   = (const float*)d_in[12];
  const float* Wd2   = (const float*)d_in[13];
  const float* Wsk0  = (const float*)d_in[14];
  const float* Wsk1  = (const float*)d_in[15];
  const float* Wsk2  = (const float*)d_in[16];
  float* out = (float*)d_out;
  float* ws  = (float*)d_ws;

  // ws layout (float units):
  // [cg 2048][mtab NN*144][counts NN][cursor NN][offsets NN+64][edge_sorted NE]
  // [nb 16][Wm1p 2048][Wm2p 5632][mixb bf16 planes ...]
  float* cgbuf = ws;
  float* mtab  = ws + 2048;
  int* counts      = (int*)(ws + 2048 + (size_t)NN*144);
  int* cursor      = counts + NN;
  int* offsets     = cursor + NN;
  int* edge_sorted = offsets + NN + 64;
  int* nb          = edge_sorted + NE;
  unsigned short* Wm1p = (unsigned short*)(nb + 16);
  unsigned short* Wm2p = Wm1p + 4096;
  unsigned short* mixb = Wm2p + 11264;

  size_t fixed_f = 2048 + (size_t)NN*144 + NN + NN + (NN+64) + NE + 16 + 2048 + 5632;
  size_t ws_f = ws_size/4;
  long long cap_rows = (ws_f > fixed_f) ? (long long)((ws_f - fixed_f)/88) : 0; // 176 bf16 = 88 f
  long long capm = cap_rows - 4096;
  if (capm < 16384) capm = 16384;
  int NC = (int)((NE + capm - 1)/capm);
  if (NC < 1) NC = 1;
  if (NC > 15) NC = 15;
  int plane_stride = (int)(NE/NC + 4096);

  hipMemsetAsync(counts, 0, 2*(size_t)NN*sizeof(int), stream);
  cg_kernel<<<11, 128, 0, stream>>>(cgbuf);
  pack_w_kernel<<<60, 256, 0, stream>>>(Wm1, Wm2, Wm1p, Wm2p);
  node_up_kernel<<<(NN*144)/256, 256, 0, stream>>>(node_feats, W_up0, W_up1, W_up2, mtab);
  hist_kernel<<<NE/256, 256, 0, stream>>>(receivers, counts);
  scan_kernel<<<1, 1024, 0, stream>>>(counts, offsets);
  scatter_kernel<<<NE/256, 256, 0, stream>>>(receivers, offsets, cursor, edge_sorted);
  find_bounds_kernel<<<NN/256, 256, 0, stream>>>(offsets, nb, NC);

  long long chunk_edges_max = NE/NC + 4096;
  int gA = (int)((chunk_edges_max + 255)/256);
  int gB = NN*8/256;
  for (int ci = 0; ci < NC; ++ci){
    edge_mix_kernel<<<gA, 256, 0, stream>>>(vectors, edge_sorted, offsets, nb,
                                            Wm0, Wm1p, Wm2p, ci, plane_stride, mixb);
    gather_kernel<<<gB, 256, 0, stream>>>(vectors, senders, edge_sorted, offsets,
                                          nb, mtab, cgbuf, mixb, ci, plane_stride, out);
  }

  node_out_kernel<<<NN*16/256, 256, 0, stream>>>(node_feats, species,
                                                 Wd0, Wd1, Wd2, Wsk0, Wsk1, Wsk2,
                                                 out, out);
}

// Round 6
// 469.644 us; speedup vs baseline: 15.3832x; 1.2503x over previous
//
#include <hip/hip_runtime.h>
#include <math.h>

#define NN 32768
#define NE 524288

typedef __attribute__((ext_vector_type(8))) short short8v;
typedef __attribute__((ext_vector_type(4))) float f32x4;

__device__ __forceinline__ float siluf(float x){
  return x * __builtin_amdgcn_rcpf(1.0f + __expf(-x));
}

__device__ __forceinline__ unsigned short f2bf(float x){
  unsigned int b = __float_as_uint(x);
  unsigned int r = ((b >> 16) & 1u) + 0x7fffu;
  return (unsigned short)((b + r) >> 16);
}

__device__ __forceinline__ unsigned int pk2(float a, float b){
  return (unsigned int)f2bf(a) | ((unsigned int)f2bf(b) << 16);
}

__device__ const int d_PL1[11] = {0,1,2,0,1,1,2,0,1,2,2};
__device__ const int d_PL2[11] = {0,1,2,1,0,2,1,2,1,0,2};
__device__ const int d_PL3[11] = {0,0,0,1,1,1,1,2,2,2,2};

// ---------------------------------------------------------------------------
// CG init (1/PATH_NORM folded). All paths have even l1+l2+l3 -> real part.
// ---------------------------------------------------------------------------
__device__ double factd(int n){ double r=1.0; for(int i=2;i<=n;++i) r*=(double)i; return r; }

__device__ double su2_elem(int l1,int l2,int l3,int m1,int m2){
  int m3=m1+m2;
  if (m3 < -l3 || m3 > l3) return 0.0;
  double pref = sqrt((double)(2*l3+1)*factd(l3+l1-l2)*factd(l3-l1+l2)*factd(l1+l2-l3)/factd(l1+l2+l3+1));
  pref *= sqrt(factd(l3+m3)*factd(l3-m3)*factd(l1-m1)*factd(l1+m1)*factd(l2-m2)*factd(l2+m2));
  double s=0.0;
  for (int k=0;k<=l1+l2-l3;++k){
    int t1=l1+l2-l3-k, t2=l1-m1-k, t3=l2+m2-k, t4=l3-l2+m1+k, t5=l3-l1-m2+k;
    if (t1<0||t2<0||t3<0||t4<0||t5<0) continue;
    double d = factd(k)*factd(t1)*factd(t2)*factd(t3)*factd(t4)*factd(t5);
    s += ((k&1)? -1.0:1.0)/d;
  }
  return pref*s;
}

__device__ void q_elem(int l,int a,int i,double& re,double& im){
  re=0.0; im=0.0;
  const double is2 = 0.7071067811865476;
  int m = a - l;
  if (m==0){ if (i==l) re=1.0; return; }
  if (m>0){
    if (i==l+m)      re = (m&1)? -is2: is2;
    else if (i==l-m) re = is2;
  } else {
    int mm=-m;
    if (i==l-mm)      im = is2;
    else if (i==l+mm) im = (mm&1)? is2 : -is2;
  }
}

__global__ void cg_kernel(float* __restrict__ cgout){
  int p = blockIdx.x;
  int t = threadIdx.x;
  if (t >= 125) return;
  int a = t/25, b = (t/5)%5, c = t%5;
  int l1=d_PL1[p], l2=d_PL2[p], l3=d_PL3[p];
  int n1=2*l1+1, n2=2*l2+1, n3=2*l3+1;
  float outv = 0.0f;
  if (a<n1 && b<n2 && c<n3){
    double acc = 0.0;
    for (int i=0;i<n1;++i)
      for (int j=0;j<n2;++j){
        int m1=i-l1, m2=j-l2;
        int m3=m1+m2;
        if (m3 < -l3 || m3 > l3) continue;
        double cv = su2_elem(l1,l2,l3,m1,m2);
        if (cv==0.0) continue;
        int k = m3 + l3;
        double a1r,a1i,a2r,a2i,a3r,a3i;
        q_elem(l1,a,i,a1r,a1i);
        q_elem(l2,b,j,a2r,a2i);
        q_elem(l3,c,k,a3r,a3i);
        double re = (a1r*a2r - a1i*a2i)*a3r + (a1r*a2i + a1i*a2r)*a3i;
        acc += cv*re;
      }
    double invn = (l3==0)? 0.5773502691896258 : 0.5;
    outv = (float)(acc*invn);
  }
  cgout[p*125 + (a*5+b)*5 + c] = outv;
}

// ---------------------------------------------------------------------------
// Node up-projection (scaled 0.25)
// ---------------------------------------------------------------------------
__global__ __launch_bounds__(256) void node_up_kernel(
    const float* __restrict__ nf,
    const float* __restrict__ W0,
    const float* __restrict__ W1,
    const float* __restrict__ W2,
    float* __restrict__ mtab)
{
  int gidx = blockIdx.x*256 + threadIdx.x;
  if (gidx >= NN*144) return;
  int n = gidx/144;
  int col = gidx - n*144;
  const float* f = nf + (size_t)n*144;
  float acc = 0.f;
  if (col < 16){
    int o = col;
    #pragma unroll
    for (int c=0;c<16;++c) acc += f[c]*W0[c*16+o];
  } else if (col < 64){
    int idx = col-16;
    int o = idx/3, i = idx - o*3;
    #pragma unroll
    for (int c=0;c<16;++c) acc += f[16+c*3+i]*W1[c*16+o];
  } else {
    int idx = col-64;
    int o = idx/5, i = idx - o*5;
    #pragma unroll
    for (int c=0;c<16;++c) acc += f[64+c*5+i]*W2[c*16+o];
  }
  mtab[gidx] = 0.25f*acc;
}

// ---------------------------------------------------------------------------
// CSR build
// ---------------------------------------------------------------------------
__global__ __launch_bounds__(256) void hist_kernel(
    const int* __restrict__ recv, int* __restrict__ counts)
{
  int e = blockIdx.x*256 + threadIdx.x;
  if (e < NE) atomicAdd(&counts[recv[e]], 1);
}

__global__ __launch_bounds__(1024) void scan_kernel(
    const int* __restrict__ counts, int* __restrict__ offsets)
{
  __shared__ int part[1024];
  int t = threadIdx.x;
  int local[32];
  int s = 0;
  #pragma unroll
  for (int i=0;i<32;++i){ local[i]=counts[t*32+i]; s+=local[i]; }
  part[t]=s;
  __syncthreads();
  for (int off=1; off<1024; off<<=1){
    int v = (t>=off)? part[t-off] : 0;
    __syncthreads();
    part[t] += v;
    __syncthreads();
  }
  int run = part[t] - s;
  #pragma unroll
  for (int i=0;i<32;++i){ offsets[t*32+i]=run; run+=local[i]; }
  if (t==1023) offsets[NN]=run;
}

__global__ __launch_bounds__(256) void scatter_kernel(
    const int* __restrict__ recv, const int* __restrict__ offsets,
    int* __restrict__ cursor, int* __restrict__ edge_sorted)
{
  int e = blockIdx.x*256 + threadIdx.x;
  if (e < NE){
    int r = recv[e];
    int pos = atomicAdd(&cursor[r], 1);
    edge_sorted[offsets[r] + pos] = e;
  }
}

__global__ __launch_bounds__(256) void find_bounds_kernel(
    const int* __restrict__ offsets, int* __restrict__ nb, int NC)
{
  int n = blockIdx.x*256 + threadIdx.x;
  if (n == 0){ nb[0] = 0; nb[NC] = NN; }
  if (n >= NN) return;
  int o0 = offsets[n], o1 = offsets[n+1];
  for (int i=1; i<NC; ++i){
    long long Ti = (long long)NE*i/NC;
    if (o0 <= Ti && Ti < o1) nb[i] = n+1;
  }
}

// ---------------------------------------------------------------------------
// Pack Wm1/Wm2 into bf16 B-fragment order.
// ---------------------------------------------------------------------------
__global__ __launch_bounds__(256) void pack_w_kernel(
    const float* __restrict__ Wm1, const float* __restrict__ Wm2,
    unsigned short* __restrict__ Wm1p, unsigned short* __restrict__ Wm2p)
{
  int t = blockIdx.x*256 + threadIdx.x;
  if (t < 4096){
    int j = t & 7, lane = (t>>3)&63, ks = (t>>9)&1, ni = t>>10;
    int k = ks*32 + (lane>>4)*8 + j;
    int col = ni*16 + (lane&15);
    Wm1p[t] = f2bf(Wm1[k*64+col]);
  }
  int t2 = t - 4096;
  if (t2 >= 0 && t2 < 11264){
    int j = t2 & 7, lane = (t2>>3)&63, ks = (t2>>9)&1, ni = t2>>10;
    int k = ks*32 + (lane>>4)*8 + j;
    int col = ni*16 + (lane&15);
    Wm2p[t2] = f2bf(Wm2[k*176+col]);
  }
}

// ---------------------------------------------------------------------------
// Edge MLP + mix with MFMA. One wave = 64 edges. 4 waves/block.
// mixb output: plane layout [path ni][slot][16 ch] bf16.
// ---------------------------------------------------------------------------
__global__ __launch_bounds__(256) void edge_mix_kernel(
    const float* __restrict__ vectors,
    const int* __restrict__ edge_sorted,
    const int* __restrict__ offsets,
    const int* __restrict__ nb,
    const float* __restrict__ Wm0,
    const unsigned short* __restrict__ Wm1p,
    const unsigned short* __restrict__ Wm2p,
    int ci, int plane_stride,
    unsigned short* __restrict__ mixb)
{
  __shared__ unsigned short lds_h[4][8*64*8];
  __shared__ float lds_s[4][64];

  int sbase = offsets[nb[ci]];
  int nE = offsets[nb[ci+1]] - sbase;
  int tid = threadIdx.x;
  int wid = tid >> 6;
  int lane = tid & 63;
  int g = lane >> 4;
  int l15 = lane & 15;
  int wb = blockIdx.x*256 + wid*64;
  int slot = wb + lane;

  float vx=0.f, vy=0.f, vz=0.f;
  if (slot < nE){
    int e = edge_sorted[sbase + slot];
    vx = vectors[(size_t)e*3+0];
    vy = vectors[(size_t)e*3+1];
    vz = vectors[(size_t)e*3+2];
  }
  float r = sqrtf(vx*vx + vy*vy + vz*vz);
  float safe = (r > 1e-9f) ? r : 1.0f;
  float inv_safe = 1.0f/safe;

  const float PIf = 3.14159265358979f;
  float xc = fminf(r*0.25f, 1.0f);
  float s1 = __sinf(PIf*xc);
  float c1 = __cosf(PIf*xc);
  float env = 0.5f*(c1 + 1.0f);
  float pref = 0.70710678118f * env * inv_safe;
  float rb[8];
  {
    float sk=s1, ck=c1;
    rb[0]=pref*sk;
    #pragma unroll
    for (int k=1;k<8;++k){
      float sn = sk*c1 + ck*s1;
      float cn = ck*c1 - sk*s1;
      sk=sn; ck=cn;
      rb[k]=pref*sk;
    }
  }

  float h[64];
  #pragma unroll
  for (int o=0;o<64;++o) h[o]=0.f;
  #pragma unroll
  for (int i=0;i<8;++i){
    float ri = rb[i];
    #pragma unroll
    for (int o=0;o<64;++o) h[o] += ri*Wm0[i*64+o];
  }

  unsigned short* Lh = lds_h[wid];
  #pragma unroll
  for (int c=0;c<8;++c){
    union { unsigned int u[4]; short8v v; } pk;
    #pragma unroll
    for (int w=0;w<4;++w){
      float a0 = siluf(h[c*8+2*w  ]*0.3535533906f);
      float a1 = siluf(h[c*8+2*w+1]*0.3535533906f);
      pk.u[w] = pk2(a0, a1);
    }
    *(short8v*)(Lh + ((size_t)(c*64 + lane))*8) = pk.v;
  }
  lds_s[wid][lane] = (r == 0.0f) ? 0.0f : 0.125f;

  __syncthreads();

  short8v a[8];
  #pragma unroll
  for (int mi=0;mi<4;++mi){
    #pragma unroll
    for (int ks=0;ks<2;++ks)
      a[mi*2+ks] = *(short8v*)(Lh + ((size_t)((ks*4+g)*64 + mi*16 + l15))*8);
  }
  #pragma unroll 1
  for (int ni=0;ni<4;++ni){
    short8v b0 = *(short8v*)(Wm1p + ((size_t)((ni*2+0)*64 + lane))*8);
    short8v b1 = *(short8v*)(Wm1p + ((size_t)((ni*2+1)*64 + lane))*8);
    int chnk = ni*2 + (l15>>3);
    int cb = l15 & 7;
    #pragma unroll
    for (int mi=0;mi<4;++mi){
      f32x4 acc = {0.f,0.f,0.f,0.f};
      acc = __builtin_amdgcn_mfma_f32_16x16x32_bf16(a[mi*2+0], b0, acc, 0,0,0);
      acc = __builtin_amdgcn_mfma_f32_16x16x32_bf16(a[mi*2+1], b1, acc, 0,0,0);
      #pragma unroll
      for (int reg=0;reg<4;++reg){
        int row = mi*16 + g*4 + reg;
        Lh[((size_t)(chnk*64 + row))*8 + cb] = f2bf(siluf(acc[reg]*0.125f));
      }
    }
  }

  short8v a2[8];
  #pragma unroll
  for (int mi=0;mi<4;++mi){
    #pragma unroll
    for (int ks=0;ks<2;++ks)
      a2[mi*2+ks] = *(short8v*)(Lh + ((size_t)((ks*4+g)*64 + mi*16 + l15))*8);
  }
  f32x4 scv[4];
  #pragma unroll
  for (int mi=0;mi<4;++mi)
    scv[mi] = *(f32x4*)(&lds_s[wid][mi*16 + g*4]);

  #pragma unroll 1
  for (int ni=0;ni<11;++ni){
    short8v b0 = *(short8v*)(Wm2p + ((size_t)((ni*2+0)*64 + lane))*8);
    short8v b1 = *(short8v*)(Wm2p + ((size_t)((ni*2+1)*64 + lane))*8);
    #pragma unroll
    for (int mi=0;mi<4;++mi){
      f32x4 acc = {0.f,0.f,0.f,0.f};
      acc = __builtin_amdgcn_mfma_f32_16x16x32_bf16(a2[mi*2+0], b0, acc, 0,0,0);
      acc = __builtin_amdgcn_mfma_f32_16x16x32_bf16(a2[mi*2+1], b1, acc, 0,0,0);
      #pragma unroll
      for (int reg=0;reg<4;++reg){
        int row = mi*16 + g*4 + reg;
        int sl = wb + row;
        if (sl < nE)
          mixb[((size_t)ni*plane_stride + sl)*16 + l15] = f2bf(acc[reg]*scv[mi][reg]);
      }
    }
  }
}

// ---------------------------------------------------------------------------
// Edge-parallel tensor product: thread per (slot, channel-quad).
// Writes msgb[slot][144] bf16 (sorted order).
// ---------------------------------------------------------------------------
template<int PIDX,int L1,int L2,int L3>
__device__ __forceinline__ void do_path4(
    const float* __restrict__ cgtab,
    const unsigned short* __restrict__ mixb,
    size_t slot, size_t plane_stride, int c0,
    const float (&y1)[3], const float (&y2)[5],
    const float (&x0)[4], const float (&x1)[4][3], const float (&x2)[4][5],
    float (&msg0)[4], float (&msg1)[4][3], float (&msg2)[4][5])
{
  constexpr int d1=2*L1+1, d2=2*L2+1, d3=2*L3+1;
  const float* cgp = cgtab + PIDX*125;

  float yv[d2];
  if constexpr (L2==0){ yv[0]=1.0f; }
  else if constexpr (L2==1){ yv[0]=y1[0]; yv[1]=y1[1]; yv[2]=y1[2]; }
  else {
    #pragma unroll
    for (int j=0;j<5;++j) yv[j]=y2[j];
  }

  float M[d1][d3];
  #pragma unroll
  for (int iu=0;iu<d1;++iu){
    #pragma unroll
    for (int k=0;k<d3;++k){
      float acc = 0.f;
      #pragma unroll
      for (int j=0;j<d2;++j) acc += yv[j]*cgp[(iu*5+j)*5+k];
      M[iu][k]=acc;
    }
  }

  const unsigned short* mp = mixb + ((size_t)PIDX*plane_stride + slot)*16 + c0;
  uint2 um = *(const uint2*)mp;
  float mx[4];
  mx[0] = __uint_as_float(um.x << 16);
  mx[1] = __uint_as_float(um.x & 0xffff0000u);
  mx[2] = __uint_as_float(um.y << 16);
  mx[3] = __uint_as_float(um.y & 0xffff0000u);

  #pragma unroll
  for (int c=0;c<4;++c){
    #pragma unroll
    for (int k=0;k<d3;++k){
      float t = 0.f;
      #pragma unroll
      for (int iu=0;iu<d1;++iu){
        float xv = (L1==0)? x0[c] : (L1==1? x1[c][iu] : x2[c][iu]);
        t += xv*M[iu][k];
      }
      if constexpr (L3==0)      msg0[c]    += mx[c]*t;
      else if constexpr (L3==1) msg1[c][k] += mx[c]*t;
      else                      msg2[c][k] += mx[c]*t;
    }
  }
}

__global__ __launch_bounds__(256) void tp_kernel(
    const float* __restrict__ vectors,
    const int* __restrict__ senders,
    const int* __restrict__ edge_sorted,
    const int* __restrict__ offsets,
    const int* __restrict__ nb,
    const float* __restrict__ mtab,
    const float* __restrict__ cgtab,
    const unsigned short* __restrict__ mixb,
    int ci, int plane_stride,
    unsigned short* __restrict__ msgb)
{
  int t = blockIdx.x*256 + threadIdx.x;
  int slot = t >> 2;
  int sbase = offsets[nb[ci]];
  int nE = offsets[nb[ci+1]] - sbase;
  if (slot >= nE) return;
  int q = t & 3;
  int c0 = q*4;
  int e = edge_sorted[sbase + slot];

  float vx = vectors[(size_t)e*3+0];
  float vy = vectors[(size_t)e*3+1];
  float vz = vectors[(size_t)e*3+2];
  float r = sqrtf(vx*vx + vy*vy + vz*vz);
  float safe = (r > 1e-9f) ? r : 1.0f;
  float inv_safe = 1.0f/safe;
  float ux=vx*inv_safe, uy=vy*inv_safe, uz=vz*inv_safe;

  const float SQ3  = 1.73205080757f;
  const float SQ15 = 3.87298334621f;
  float y1[3] = { SQ3*uy, SQ3*uz, SQ3*ux };
  float y2[5] = { SQ15*ux*uy, SQ15*uy*uz, 1.11803398875f*(3.f*uz*uz-1.f),
                  SQ15*ux*uz, 1.93649167310f*(ux*ux-uy*uy) };

  const float* xp = mtab + (size_t)senders[e]*144;
  float x0[4];
  float x1[4][3];
  float x2[4][5];
  #pragma unroll
  for (int c=0;c<4;++c) x0[c] = xp[c0+c];
  #pragma unroll
  for (int c=0;c<4;++c){
    #pragma unroll
    for (int i=0;i<3;++i) x1[c][i] = xp[16 + (c0+c)*3 + i];
  }
  #pragma unroll
  for (int c=0;c<4;++c){
    #pragma unroll
    for (int i=0;i<5;++i) x2[c][i] = xp[64 + (c0+c)*5 + i];
  }

  float msg0[4];
  float msg1[4][3];
  float msg2[4][5];
  #pragma unroll
  for (int c=0;c<4;++c){
    msg0[c]=0.f;
    #pragma unroll
    for (int i=0;i<3;++i) msg1[c][i]=0.f;
    #pragma unroll
    for (int i=0;i<5;++i) msg2[c][i]=0.f;
  }

  size_t sl = (size_t)slot;
  do_path4< 0,0,0,0>(cgtab,mixb,sl,plane_stride,c0,y1,y2,x0,x1,x2,msg0,msg1,msg2);
  do_path4< 1,1,1,0>(cgtab,mixb,sl,plane_stride,c0,y1,y2,x0,x1,x2,msg0,msg1,msg2);
  do_path4< 2,2,2,0>(cgtab,mixb,sl,plane_stride,c0,y1,y2,x0,x1,x2,msg0,msg1,msg2);
  do_path4< 3,0,1,1>(cgtab,mixb,sl,plane_stride,c0,y1,y2,x0,x1,x2,msg0,msg1,msg2);
  do_path4< 4,1,0,1>(cgtab,mixb,sl,plane_stride,c0,y1,y2,x0,x1,x2,msg0,msg1,msg2);
  do_path4< 5,1,2,1>(cgtab,mixb,sl,plane_stride,c0,y1,y2,x0,x1,x2,msg0,msg1,msg2);
  do_path4< 6,2,1,1>(cgtab,mixb,sl,plane_stride,c0,y1,y2,x0,x1,x2,msg0,msg1,msg2);
  do_path4< 7,0,2,2>(cgtab,mixb,sl,plane_stride,c0,y1,y2,x0,x1,x2,msg0,msg1,msg2);
  do_path4< 8,1,1,2>(cgtab,mixb,sl,plane_stride,c0,y1,y2,x0,x1,x2,msg0,msg1,msg2);
  do_path4< 9,2,0,2>(cgtab,mixb,sl,plane_stride,c0,y1,y2,x0,x1,x2,msg0,msg1,msg2);
  do_path4<10,2,2,2>(cgtab,mixb,sl,plane_stride,c0,y1,y2,x0,x1,x2,msg0,msg1,msg2);

  unsigned short* mr = msgb + (size_t)slot*144;
  // msg0 -> cols [c0, c0+4)
  {
    uint2 w;
    w.x = pk2(msg0[0], msg0[1]);
    w.y = pk2(msg0[2], msg0[3]);
    *(uint2*)(mr + c0) = w;
  }
  // msg1 -> cols [16+c0*3, +12)
  {
    unsigned short* p = mr + 16 + c0*3;
    uint2 w0, w1;
    w0.x = pk2(msg1[0][0], msg1[0][1]);
    w0.y = pk2(msg1[0][2], msg1[1][0]);
    w1.x = pk2(msg1[1][1], msg1[1][2]);
    w1.y = pk2(msg1[2][0], msg1[2][1]);
    *(uint2*)(p) = w0;
    *(uint2*)(p+4) = w1;
    uint2 w2;
    w2.x = pk2(msg1[2][2], msg1[3][0]);
    w2.y = pk2(msg1[3][1], msg1[3][2]);
    *(uint2*)(p+8) = w2;
  }
  // msg2 -> cols [64+c0*5, +20)
  {
    unsigned short* p = mr + 64 + c0*5;
    #pragma unroll
    for (int w=0; w<5; ++w){
      int i0 = w*4;
      // flat index f = c*5+i
      float v0 = msg2[(i0+0)/5][(i0+0)%5];
      float v1 = msg2[(i0+1)/5][(i0+1)%5];
      float v2 = msg2[(i0+2)/5][(i0+2)%5];
      float v3 = msg2[(i0+3)/5][(i0+3)%5];
      uint2 ww;
      ww.x = pk2(v0, v1);
      ww.y = pk2(v2, v3);
      *(uint2*)(p + i0) = ww;
    }
  }
}

// ---------------------------------------------------------------------------
// Segmented sum over sorted msgb rows: thread per (node, col).
// ---------------------------------------------------------------------------
__global__ __launch_bounds__(256) void seg_sum_kernel(
    const int* __restrict__ offsets,
    const int* __restrict__ nb,
    const unsigned short* __restrict__ msgb,
    int ci,
    float* __restrict__ out)
{
  int t = blockIdx.x*256 + threadIdx.x;
  int n = t/144;
  int col = t - n*144;
  if (n >= NN) return;
  int nlo = nb[ci], nhi = nb[ci+1];
  if (n < nlo || n >= nhi) return;
  int cbase = offsets[nlo];
  int j0 = offsets[n] - cbase;
  int j1 = offsets[n+1] - cbase;
  float acc = 0.f;
  for (int j=j0; j<j1; ++j){
    unsigned short v = msgb[(size_t)j*144 + col];
    acc += __uint_as_float(((unsigned int)v) << 16);
  }
  out[(size_t)n*144 + col] = acc;
}

// ---------------------------------------------------------------------------
// Final node update, in-place on out.
// ---------------------------------------------------------------------------
__global__ __launch_bounds__(256) void node_out_kernel(
    const float* __restrict__ nf,
    const int* __restrict__ species,
    const float* __restrict__ Wd0,
    const float* __restrict__ Wd1,
    const float* __restrict__ Wd2,
    const float* __restrict__ Wsk0,
    const float* __restrict__ Wsk1,
    const float* __restrict__ Wsk2,
    const float* agg,
    float* out)
{
  int t = blockIdx.x*256 + threadIdx.x;
  int n = t >> 4;
  int o = t & 15;
  if (n >= NN) return;
  const float* an = agg + (size_t)n*144;
  const float* f  = nf  + (size_t)n*144;
  int sp = species[n];
  const float* wk0 = Wsk0 + sp*768;
  const float* wk1 = Wsk1 + sp*256;
  const float* wk2 = Wsk2 + sp*256;

  float sa0=0,sa1=0,sa2=0, sf0=0,sf1=0,sf2=0;
  #pragma unroll
  for (int c=0;c<16;++c){
    float a = an[c], ff = f[c];
    sa0 += a*Wd0[c*48+o];
    sa1 += a*Wd0[c*48+16+o];
    sa2 += a*Wd0[c*48+32+o];
    sf0 += ff*wk0[c*48+o];
    sf1 += ff*wk0[c*48+16+o];
    sf2 += ff*wk0[c*48+32+o];
  }
  float s0 = 0.0625f*sa0 + 0.25f*sf0;
  float s1 = 0.0625f*sa1 + 0.25f*sf1;
  float s2 = 0.0625f*sa2 + 0.25f*sf2;
  float scvv = siluf(s0);
  float g1  = siluf(s1);
  float g2  = siluf(s2);

  float v[3];
  #pragma unroll
  for (int i=0;i<3;++i){
    float av=0, fv=0;
    #pragma unroll
    for (int c=0;c<16;++c){
      av += an[16+c*3+i]*Wd1[c*16+o];
      fv += f[16+c*3+i]*wk1[c*16+o];
    }
    v[i] = (0.0625f*av + 0.25f*fv)*g1;
  }
  float q[5];
  #pragma unroll
  for (int i=0;i<5;++i){
    float av=0, fv=0;
    #pragma unroll
    for (int c=0;c<16;++c){
      av += an[64+c*5+i]*Wd2[c*16+o];
      fv += f[64+c*5+i]*wk2[c*16+o];
    }
    q[i] = (0.0625f*av + 0.25f*fv)*g2;
  }

  float* on = out + (size_t)n*144;
  on[o] = scvv;
  #pragma unroll
  for (int i=0;i<3;++i) on[16+o*3+i] = v[i];
  #pragma unroll
  for (int i=0;i<5;++i) on[64+o*5+i] = q[i];
}

// ---------------------------------------------------------------------------
extern "C" void kernel_launch(void* const* d_in, const int* in_sizes, int n_in,
                              void* d_out, int out_size, void* d_ws, size_t ws_size,
                              hipStream_t stream)
{
  const float* vectors    = (const float*)d_in[0];
  const float* node_feats = (const float*)d_in[1];
  const int*   species    = (const int*)d_in[2];
  const int*   senders    = (const int*)d_in[3];
  const int*   receivers  = (const int*)d_in[4];
  const float* W_up0 = (const float*)d_in[5];
  const float* W_up1 = (const float*)d_in[6];
  const float* W_up2 = (const float*)d_in[7];
  const float* Wm0   = (const float*)d_in[8];
  const float* Wm1   = (const float*)d_in[9];
  const float* Wm2   = (const float*)d_in[10];
  const float* Wd0   = (const float*)d_in[11];
  const float* Wd1   = (const float*)d_in[12];
  const float* Wd2   = (const float*)d_in[13];
  const float* Wsk0  = (const float*)d_in[14];
  const float* Wsk1  = (const float*)d_in[15];
  const float* Wsk2  = (const float*)d_in[16];
  float* out = (float*)d_out;
  float* ws  = (float*)d_ws;

  // ws layout (float units):
  // [cg 2048][mtab NN*144][counts NN][cursor NN][offsets NN+64][edge_sorted NE]
  // [nb 16][Wm1p 2048][Wm2p 5632][mixb bf16 planes][msgb bf16 rows]
  float* cgbuf = ws;
  float* mtab  = ws + 2048;
  int* counts      = (int*)(ws + 2048 + (size_t)NN*144);
  int* cursor      = counts + NN;
  int* offsets     = cursor + NN;
  int* edge_sorted = offsets + NN + 64;
  int* nb          = edge_sorted + NE;
  unsigned short* Wm1p = (unsigned short*)(nb + 16);
  unsigned short* Wm2p = Wm1p + 4096;
  unsigned short* mixb = Wm2p + 11264;

  size_t fixed_f = 2048 + (size_t)NN*144 + NN + NN + (NN+64) + NE + 16 + 2048 + 5632;
  size_t ws_f = ws_size/4;
  // per-edge: mixb 176 bf16 (88 f) + msgb 144 bf16 (72 f) = 160 f
  long long cap_rows = (ws_f > fixed_f) ? (long long)((ws_f - fixed_f)/160) : 0;
  long long capm = cap_rows - 4096;
  if (capm < 16384) capm = 16384;
  int NC = (int)((NE + capm - 1)/capm);
  if (NC < 1) NC = 1;
  if (NC > 15) NC = 15;
  int plane_stride = (int)(NE/NC + 4096);
  unsigned short* msgb = mixb + (size_t)11*plane_stride*16;

  hipMemsetAsync(counts, 0, 2*(size_t)NN*sizeof(int), stream);
  cg_kernel<<<11, 128, 0, stream>>>(cgbuf);
  pack_w_kernel<<<60, 256, 0, stream>>>(Wm1, Wm2, Wm1p, Wm2p);
  node_up_kernel<<<(NN*144)/256, 256, 0, stream>>>(node_feats, W_up0, W_up1, W_up2, mtab);
  hist_kernel<<<NE/256, 256, 0, stream>>>(receivers, counts);
  scan_kernel<<<1, 1024, 0, stream>>>(counts, offsets);
  scatter_kernel<<<NE/256, 256, 0, stream>>>(receivers, offsets, cursor, edge_sorted);
  find_bounds_kernel<<<NN/256, 256, 0, stream>>>(offsets, nb, NC);

  long long chunk_edges_max = NE/NC + 4096;
  int gA  = (int)((chunk_edges_max + 255)/256);
  int gTP = (int)((chunk_edges_max*4 + 255)/256);
  int gSS = (NN*144 + 255)/256;
  for (int ci = 0; ci < NC; ++ci){
    edge_mix_kernel<<<gA, 256, 0, stream>>>(vectors, edge_sorted, offsets, nb,
                                            Wm0, Wm1p, Wm2p, ci, plane_stride, mixb);
    tp_kernel<<<gTP, 256, 0, stream>>>(vectors, senders, edge_sorted, offsets, nb,
                                       mtab, cgbuf, mixb, ci, plane_stride, msgb);
    seg_sum_kernel<<<gSS, 256, 0, stream>>>(offsets, nb, msgb, ci, out);
  }

  node_out_kernel<<<NN*16/256, 256, 0, stream>>>(node_feats, species,
                                                 Wd0, Wd1, Wd2, Wsk0, Wsk1, Wsk2,
                                                 out, out);
}